// Round 1
// baseline (799.295 us; speedup 1.0000x reference)
//
#include <hip/hip_runtime.h>

typedef float  f32x4  __attribute__((ext_vector_type(4)));
typedef __bf16 bf16x8 __attribute__((ext_vector_type(8)));
typedef unsigned short u16x8 __attribute__((ext_vector_type(8)));

__device__ inline unsigned short f2b(float f) {
    unsigned u = __builtin_bit_cast(unsigned, f);
    u += 0x7fffu + ((u >> 16) & 1u);       // round-to-nearest-even
    return (unsigned short)(u >> 16);
}

__device__ inline f32x4 mfma16(bf16x8 a, bf16x8 b, f32x4 c) {
    return __builtin_amdgcn_mfma_f32_16x16x32_bf16(a, b, c, 0, 0, 0);
}

__device__ inline bf16x8 cvt8(f32x4 a, f32x4 b) {
    u16x8 v;
    v[0] = f2b(a[0]); v[1] = f2b(a[1]); v[2] = f2b(a[2]); v[3] = f2b(a[3]);
    v[4] = f2b(b[0]); v[5] = f2b(b[1]); v[6] = f2b(b[2]); v[7] = f2b(b[3]);
    return __builtin_bit_cast(bf16x8, v);
}

__device__ inline bf16x8 ldsA(const unsigned short* base, int frag, int lane) {
    return __builtin_bit_cast(bf16x8,
        *reinterpret_cast<const u16x8*>(base + ((frag * 64 + lane) << 3)));
}

// ============================ CSR build ============================
__global__ void k_hist(const int* __restrict__ erow, int* __restrict__ cnt, int E)
{
    int i = blockIdx.x * 256 + threadIdx.x;
    if (i < E) atomicAdd(&cnt[erow[i]], 1);
}

// single-block exclusive scan of cnt[0..N) -> off, woff; off[N] = E
__global__ void k_scan(const int* __restrict__ cnt, int* __restrict__ off,
                       int* __restrict__ woff, int N, int E)
{
    __shared__ int wsum[16];
    const int t = threadIdx.x;            // 1024 threads
    const int lane = t & 63, w = t >> 6;
    const int chunk = (N + 1023) >> 10;
    const int lo = t * chunk;
    const int hi = (lo + chunk < N) ? lo + chunk : N;
    int s = 0;
    for (int i = lo; i < hi; ++i) s += cnt[i];
    int sc = s;
#pragma unroll
    for (int d = 1; d < 64; d <<= 1) {
        int v = __shfl_up(sc, d, 64);
        if (lane >= d) sc += v;
    }
    if (lane == 63) wsum[w] = sc;
    __syncthreads();
    if (w == 0 && lane < 16) {
        int v = wsum[lane];
        int scw = v;
#pragma unroll
        for (int d = 1; d < 16; d <<= 1) {
            int u = __shfl_up(scw, d, 16);
            if (lane >= d) scw += u;
        }
        wsum[lane] = scw - v;             // exclusive wave prefix
    }
    __syncthreads();
    int run = wsum[w] + (sc - s);         // exclusive prefix for this thread
    for (int i = lo; i < hi; ++i) {
        off[i] = run; woff[i] = run;
        run += cnt[i];
    }
    if (t == 0) off[N] = E;
}

__global__ void k_scatter(const int* __restrict__ erow, const int* __restrict__ ecol,
                          int* __restrict__ woff, int* __restrict__ scol, int E)
{
    int i = blockIdx.x * 256 + threadIdx.x;
    if (i < E) {
        int pos = atomicAdd(&woff[erow[i]], 1);
        scol[pos] = ecol[i];
    }
}

// ===================== SORTED EDGE PASS (no global atomics) =====================
// One wave owns 8 nodes' contiguous segment of row-sorted edges. Edge MLP runs
// in 16-edge MFMA groups (h[row] from LDS tile, h[col] gathered 1 group ahead).
// edge_feat is transposed via the per-wave stash, then a sequential 16-step
// segmented running-sum in registers replaces the atomic scatter: each node is
// one contiguous run -> one plain coalesced 256B store. cnt comes from offsets.
__global__ __launch_bounds__(512, 4) void egcl_edge_sorted(
    const unsigned short* __restrict__ hb,
    const float* __restrict__ coord,
    const int* __restrict__ off, const int* __restrict__ scol,
    const float* __restrict__ We1, const float* __restrict__ be1,
    const float* __restrict__ We2, const float* __restrict__ be2,
    const float* __restrict__ Wc1, const float* __restrict__ bc1,
    const float* __restrict__ Wc2,
    float* __restrict__ aggf, float* __restrict__ cout, int N)
{
    __shared__ __align__(16) unsigned short A1[16 * 512];
    __shared__ __align__(16) unsigned short A2[8 * 512];
    __shared__ __align__(16) unsigned short A3[8 * 512];
    __shared__ __align__(16) float bv[5][64];
    __shared__ __align__(16) unsigned stl[8][16 * 33];   // per-wave transpose stash
    __shared__ __align__(16) unsigned short hl[8][8 * 72]; // per-wave 8 node h rows (padded)
    __shared__ __align__(16) float cl[8][32];              // per-wave 8 node coords (x,y,z,pad)

    const int t = threadIdx.x;
    for (int i = t; i < 8192; i += 512) {
        int j = i & 7, lane = (i >> 3) & 63, fi = i >> 9;
        int mt = fi >> 2, ks = fi & 3;
        int in_ch = ks * 32 + ((lane >> 4) << 3) + j;
        int out   = mt * 16 + (lane & 15);
        A1[i] = f2b(We1[in_ch * 64 + out]);
    }
    for (int i = t; i < 4096; i += 512) {
        int j = i & 7, lane = (i >> 3) & 63, fi = i >> 9;
        int mt = fi >> 1, ks = fi & 1;
        int c   = (ks * 2 + (j >> 2)) * 16 + ((lane >> 4) & 3) * 4 + (j & 3);
        int out = mt * 16 + (lane & 15);
        A2[i] = f2b(We2[c * 64 + out]);
        A3[i] = f2b(Wc1[c * 64 + out]);
    }
    if (t < 64) {
        bv[0][t] = be1[t]; bv[1][t] = We1[128 * 64 + t];
        bv[2][t] = be2[t]; bv[3][t] = bc1[t]; bv[4][t] = Wc2[t];
    }
    __syncthreads();

    const int lane = t & 63;
    const int l16 = lane & 15, lq = lane >> 4;
    const int w = t >> 6;
    unsigned* st = stl[w];
    unsigned short* hrw = hl[w];
    float* crw = cl[w];

    const int nT = N >> 3;
    const int tile = blockIdx.x * 8 + w;
    if (tile >= nT) return;
    const int nb = tile << 3;

    // ---- stage the tile's 8 node rows (h + coord) into wave-private LDS
    {
        int row = lane >> 3, ck = lane & 7;
        *reinterpret_cast<u16x8*>(hrw + row * 72 + ck * 8) =
            *reinterpret_cast<const u16x8*>(hb + (size_t)(nb + row) * 64 + ck * 8);
    }
    if (lane < 32) {
        int nn = lane >> 2, c4 = lane & 3;
        crw[lane] = (c4 < 3) ? coord[(size_t)(nb + nn) * 3 + c4] : 0.f;
    }

    int ok[9];
#pragma unroll
    for (int k = 0; k < 9; ++k) ok[k] = off[nb + k];
    const int s0 = ok[0], s1 = ok[8];
    const int dd0 = ok[1]-ok[0], dd1 = ok[2]-ok[1], dd2 = ok[3]-ok[2], dd3 = ok[4]-ok[3];
    const int dd4 = ok[5]-ok[4], dd5 = ok[6]-ok[5], dd6 = ok[7]-ok[6], dd7 = ok[8]-ok[7];

    int cur = -1; float accv = 0.f, caccv = 0.f;
    auto FLUSH = [&]() {
        if (cur >= 0) {
            aggf[(size_t)(nb + cur) * 64 + lane] = accv;
            if (lane < 3) {
                int cc = cur==0?dd0:cur==1?dd1:cur==2?dd2:cur==3?dd3:
                         cur==4?dd4:cur==5?dd5:cur==6?dd6:dd7;
                cout[(size_t)(nb + cur) * 3 + lane] = caccv * (1.f / fmaxf((float)cc, 1.f));
            }
        }
    };

    const int nE = s1 - s0;
    if (nE > 0) {
        const int s1m1 = s1 - 1;
        const int nG = (nE + 15) >> 4;

        // prologue: group0 data + group1 indices
        int gb = s0;
        int p  = gb + l16;
        {
            int pm = (p < s1m1) ? p : s1m1;
            int c0 = scol[pm];
            const u16x8* hp = reinterpret_cast<const u16x8*>(hb + (size_t)c0 * 64);
            // fallthrough loads below
            // (kept inline to let compiler pipeline)
            u16x8 h0 = hp[lq], h1 = hp[4 + lq];
            float cx = 0.f, cy = 0.f, cz = 0.f;
            if (lq == 1) { const float* pp = coord + (size_t)c0 * 3; cx = pp[0]; cy = pp[1]; cz = pp[2]; }
            int q1 = gb + 16 + l16;
            int c1 = scol[(q1 < s1m1) ? q1 : s1m1];

            u16x8 hc0 = h0, hc1 = h1;
            float cpx = cx, cpy = cy, cpz = cz;

            for (int g = 0; g < nG; ++g) {
                // ---- stage next group's data
                u16x8 nh0, nh1;
                {
                    const u16x8* np = reinterpret_cast<const u16x8*>(hb + (size_t)c1 * 64);
                    nh0 = np[lq]; nh1 = np[4 + lq];
                }
                float nx = 0.f, ny = 0.f, nz = 0.f;
                if (lq == 1) { const float* pp = coord + (size_t)c1 * 3; nx = pp[0]; ny = pp[1]; nz = pp[2]; }
                int q2 = gb + 32 + l16;
                int c2 = scol[(q2 < s1m1) ? q2 : s1m1];

                // ---- node index within tile for this lane's edge
                int ni = 0;
#pragma unroll
                for (int k = 1; k < 8; ++k) ni += (p >= ok[k]) ? 1 : 0;

                // ---- operands
                bf16x8 bR[2];
                bR[0] = __builtin_bit_cast(bf16x8,
                        *reinterpret_cast<const u16x8*>(hrw + ni * 72 + lq * 8));
                bR[1] = __builtin_bit_cast(bf16x8,
                        *reinterpret_cast<const u16x8*>(hrw + ni * 72 + (4 + lq) * 8));
                bf16x8 bC[2] = { __builtin_bit_cast(bf16x8, hc0), __builtin_bit_cast(bf16x8, hc1) };

                float prx = crw[ni * 4 + 0], pry = crw[ni * 4 + 1], prz = crw[ni * 4 + 2];
                float pcx = __shfl(cpx, 16 + l16, 64);
                float pcy = __shfl(cpy, 16 + l16, 64);
                float pcz = __shfl(cpz, 16 + l16, 64);
                float dx = prx - pcx, dy = pry - pcy, dz = prz - pcz;
                float rad = dx * dx + dy * dy + dz * dz;

                // ---- layer 1
                f32x4 a1[4];
#pragma unroll
                for (int mt = 0; mt < 4; ++mt)
                    a1[mt] = *reinterpret_cast<const f32x4*>(&bv[0][mt * 16 + lq * 4]);
#pragma unroll
                for (int ks = 0; ks < 2; ++ks)
#pragma unroll
                    for (int mt = 0; mt < 4; ++mt)
                        a1[mt] = mfma16(ldsA(A1, mt * 4 + ks, lane), bR[ks], a1[mt]);
#pragma unroll
                for (int ks = 0; ks < 2; ++ks)
#pragma unroll
                    for (int mt = 0; mt < 4; ++mt)
                        a1[mt] = mfma16(ldsA(A1, mt * 4 + 2 + ks, lane), bC[ks], a1[mt]);
#pragma unroll
                for (int mt = 0; mt < 4; ++mt) {
                    f32x4 wv = *reinterpret_cast<const f32x4*>(&bv[1][mt * 16 + lq * 4]);
#pragma unroll
                    for (int rr = 0; rr < 4; ++rr)
                        a1[mt][rr] = fmaxf(a1[mt][rr] + rad * wv[rr], 0.f);
                }

                // ---- layer 2
                bf16x8 b2[2] = { cvt8(a1[0], a1[1]), cvt8(a1[2], a1[3]) };
                f32x4 a2[4];
#pragma unroll
                for (int mt = 0; mt < 4; ++mt)
                    a2[mt] = *reinterpret_cast<const f32x4*>(&bv[2][mt * 16 + lq * 4]);
#pragma unroll
                for (int ks = 0; ks < 2; ++ks)
#pragma unroll
                    for (int mt = 0; mt < 4; ++mt)
                        a2[mt] = mfma16(ldsA(A2, mt * 2 + ks, lane), b2[ks], a2[mt]);
#pragma unroll
                for (int mt = 0; mt < 4; ++mt)
#pragma unroll
                    for (int rr = 0; rr < 4; ++rr)
                        a2[mt][rr] = fmaxf(a2[mt][rr], 0.f);

                // ---- stash a2 (transpose): st[edge][cp] holds channels {2cp, 2cp+1}
#pragma unroll
                for (int mt = 0; mt < 4; ++mt) {
                    unsigned w0 = (unsigned)f2b(a2[mt][0]) | ((unsigned)f2b(a2[mt][1]) << 16);
                    unsigned w1 = (unsigned)f2b(a2[mt][2]) | ((unsigned)f2b(a2[mt][3]) << 16);
                    st[l16 * 33 + mt * 8 + lq * 2 + 0] = w0;
                    st[l16 * 33 + mt * 8 + lq * 2 + 1] = w1;
                }

                // ---- gate (MFMAs overlap the stash writes)
                bf16x8 b3[2] = { cvt8(a2[0], a2[1]), cvt8(a2[2], a2[3]) };
                f32x4 a3[4];
#pragma unroll
                for (int mt = 0; mt < 4; ++mt)
                    a3[mt] = *reinterpret_cast<const f32x4*>(&bv[3][mt * 16 + lq * 4]);
#pragma unroll
                for (int ks = 0; ks < 2; ++ks)
#pragma unroll
                    for (int mt = 0; mt < 4; ++mt)
                        a3[mt] = mfma16(ldsA(A3, mt * 2 + ks, lane), b3[ks], a3[mt]);
                float gg = 0.f;
#pragma unroll
                for (int mt = 0; mt < 4; ++mt) {
                    f32x4 wv = *reinterpret_cast<const f32x4*>(&bv[4][mt * 16 + lq * 4]);
#pragma unroll
                    for (int rr = 0; rr < 4; ++rr)
                        gg += fmaxf(a3[mt][rr], 0.f) * wv[rr];
                }
                gg += __shfl_xor(gg, 16, 64);
                gg += __shfl_xor(gg, 32, 64);

                float dsel = (lq == 0) ? dx : (lq == 1) ? dy : dz;
                float val  = fminf(fmaxf(dsel * gg, -100.f), 100.f);

                // ---- sequential segmented accumulation over the 16 edges
#pragma unroll
                for (int e = 0; e < 16; ++e) {
                    if (gb + e < s1) {                 // wave-uniform guard
                        int nv = __shfl(ni, e, 64);    // node of edge e (uniform)
                        unsigned wrd = st[e * 33 + (lane >> 1)];
                        float v = __builtin_bit_cast(float,
                                  (lane & 1) ? (wrd & 0xffff0000u) : (wrd << 16));
                        float cv = __shfl(val, ((lane & 3) << 4) + e, 64);
                        if (nv != cur) { FLUSH(); cur = nv; accv = v; caccv = cv; }
                        else           { accv += v; caccv += cv; }
                    }
                }

                // ---- rotate
                gb += 16; p += 16;
                c1 = c2;
                hc0 = nh0; hc1 = nh1;
                cpx = nx; cpy = ny; cpz = nz;
            }
        }
        FLUSH();
    }

    // zero-fill nodes with no edges (every node row written exactly once)
#pragma unroll
    for (int k = 0; k < 8; ++k) {
        if (ok[k + 1] == ok[k]) {
            aggf[(size_t)(nb + k) * 64 + lane] = 0.f;
            if (lane < 3) cout[(size_t)(nb + k) * 3 + lane] = 0.f;
        }
    }
}

// ===================== FALLBACK EDGE PASS (atomic, f32) =====================
__global__ __launch_bounds__(512, 4) void egcl_edge_fb(
    const float* __restrict__ h, const float* __restrict__ coord,
    const int* __restrict__ erow, const int* __restrict__ ecol,
    const float* __restrict__ We1, const float* __restrict__ be1,
    const float* __restrict__ We2, const float* __restrict__ be2,
    const float* __restrict__ Wc1, const float* __restrict__ bc1,
    const float* __restrict__ Wc2,
    float* __restrict__ aggf, float* __restrict__ cacc, int E)
{
    __shared__ __align__(16) unsigned short A1[16 * 512];
    __shared__ __align__(16) unsigned short A2[8 * 512];
    __shared__ __align__(16) unsigned short A3[8 * 512];
    __shared__ __align__(16) float bv[5][64];

    const int t = threadIdx.x;
    for (int i = t; i < 8192; i += 512) {
        int j = i & 7, lane = (i >> 3) & 63, fi = i >> 9;
        int mt = fi >> 2, ks = fi & 3;
        int in_ch = ks * 32 + ((lane >> 4) << 3) + j;
        int out   = mt * 16 + (lane & 15);
        A1[i] = f2b(We1[in_ch * 64 + out]);
    }
    for (int i = t; i < 4096; i += 512) {
        int j = i & 7, lane = (i >> 3) & 63, fi = i >> 9;
        int mt = fi >> 1, ks = fi & 1;
        int c   = (ks * 2 + (j >> 2)) * 16 + ((lane >> 4) & 3) * 4 + (j & 3);
        int out = mt * 16 + (lane & 15);
        A2[i] = f2b(We2[c * 64 + out]);
        A3[i] = f2b(Wc1[c * 64 + out]);
    }
    if (t < 64) {
        bv[0][t] = be1[t]; bv[1][t] = We1[128 * 64 + t];
        bv[2][t] = be2[t]; bv[3][t] = bc1[t]; bv[4][t] = Wc2[t];
    }
    __syncthreads();

    const int lane = t & 63;
    const int l16 = lane & 15, lq = lane >> 4;
    const int stride = gridDim.x * 8;
    const int wid = (blockIdx.x << 3) + (t >> 6);
    const int ntile = E >> 4;

    for (int tile = wid; tile < ntile; tile += stride) {
        const int e = (tile << 4) + l16;
        const int r = erow[e], c = ecol[e];
        const float* pr = coord + (size_t)r * 3;
        const float* pc = coord + (size_t)c * 3;
        float dx = pr[0] - pc[0], dy = pr[1] - pc[1], dz = pr[2] - pc[2];
        float rad = dx * dx + dy * dy + dz * dz;
        const f32x4* hr = reinterpret_cast<const f32x4*>(h + (size_t)r * 64);
        const f32x4* hc = reinterpret_cast<const f32x4*>(h + (size_t)c * 64);
        bf16x8 bR[2], bC[2];
#pragma unroll
        for (int ks = 0; ks < 2; ++ks) {
            bR[ks] = cvt8(hr[ks * 8 + lq * 2], hr[ks * 8 + lq * 2 + 1]);
            bC[ks] = cvt8(hc[ks * 8 + lq * 2], hc[ks * 8 + lq * 2 + 1]);
        }
        f32x4 a1[4];
#pragma unroll
        for (int mt = 0; mt < 4; ++mt)
            a1[mt] = *reinterpret_cast<const f32x4*>(&bv[0][mt * 16 + lq * 4]);
#pragma unroll
        for (int ks = 0; ks < 2; ++ks)
#pragma unroll
            for (int mt = 0; mt < 4; ++mt)
                a1[mt] = mfma16(ldsA(A1, mt * 4 + ks, lane), bR[ks], a1[mt]);
#pragma unroll
        for (int ks = 0; ks < 2; ++ks)
#pragma unroll
            for (int mt = 0; mt < 4; ++mt)
                a1[mt] = mfma16(ldsA(A1, mt * 4 + 2 + ks, lane), bC[ks], a1[mt]);
#pragma unroll
        for (int mt = 0; mt < 4; ++mt) {
            f32x4 wv = *reinterpret_cast<const f32x4*>(&bv[1][mt * 16 + lq * 4]);
#pragma unroll
            for (int rr = 0; rr < 4; ++rr)
                a1[mt][rr] = fmaxf(a1[mt][rr] + rad * wv[rr], 0.f);
        }
        bf16x8 b2[2] = { cvt8(a1[0], a1[1]), cvt8(a1[2], a1[3]) };
        f32x4 a2[4];
#pragma unroll
        for (int mt = 0; mt < 4; ++mt)
            a2[mt] = *reinterpret_cast<const f32x4*>(&bv[2][mt * 16 + lq * 4]);
#pragma unroll
        for (int ks = 0; ks < 2; ++ks)
#pragma unroll
            for (int mt = 0; mt < 4; ++mt)
                a2[mt] = mfma16(ldsA(A2, mt * 2 + ks, lane), b2[ks], a2[mt]);
#pragma unroll
        for (int mt = 0; mt < 4; ++mt)
#pragma unroll
            for (int rr = 0; rr < 4; ++rr) {
                a2[mt][rr] = fmaxf(a2[mt][rr], 0.f);
                atomicAdd(&aggf[(size_t)r * 64 + mt * 16 + lq * 4 + rr], a2[mt][rr]);
            }
        bf16x8 b3[2] = { cvt8(a2[0], a2[1]), cvt8(a2[2], a2[3]) };
        f32x4 a3[4];
#pragma unroll
        for (int mt = 0; mt < 4; ++mt)
            a3[mt] = *reinterpret_cast<const f32x4*>(&bv[3][mt * 16 + lq * 4]);
#pragma unroll
        for (int ks = 0; ks < 2; ++ks)
#pragma unroll
            for (int mt = 0; mt < 4; ++mt)
                a3[mt] = mfma16(ldsA(A3, mt * 2 + ks, lane), b3[ks], a3[mt]);
        float gg = 0.f;
#pragma unroll
        for (int mt = 0; mt < 4; ++mt) {
            f32x4 wv = *reinterpret_cast<const f32x4*>(&bv[4][mt * 16 + lq * 4]);
#pragma unroll
            for (int rr = 0; rr < 4; ++rr)
                gg += fmaxf(a3[mt][rr], 0.f) * wv[rr];
        }
        gg += __shfl_xor(gg, 16, 64);
        gg += __shfl_xor(gg, 32, 64);
        float dsel = (lq == 0) ? dx : (lq == 1) ? dy : dz;
        float val  = (lq == 3) ? 1.0f : fminf(fmaxf(dsel * gg, -100.f), 100.f);
        atomicAdd(&cacc[(size_t)r * 4 + lq], val);
    }
}

// ============================== NODE PASS ==============================
__device__ inline void stage_wblock(unsigned short* dst, const float* src, int t, int nthr) {
    for (int i = t; i < 4096; i += nthr) {
        int k = i >> 6, n = i & 63;
        int pos = (((n >> 4) * 2 + (k >> 5)) * 64 + ((((k >> 3) & 3) << 4) | (n & 15))) * 8 + (k & 7);
        dst[pos] = f2b(src[i]);
    }
}

__device__ inline bf16x8 ldsB(const unsigned short* base, int nt, int ks, int lane) {
    return __builtin_bit_cast(bf16x8,
        *reinterpret_cast<const u16x8*>(base + (((nt * 2 + ks) * 64 + lane) << 3)));
}

__global__ __launch_bounds__(256) void egcl_node_fb(
    const float* __restrict__ h, const float* __restrict__ aggf,
    const float* __restrict__ Wn1, const float* __restrict__ bn1,
    const float* __restrict__ Wn2, const float* __restrict__ bn2,
    float* __restrict__ hout, int N)
{
    __shared__ __align__(16) unsigned short wlds[3][4096];
    __shared__ __align__(16) unsigned short mlds[4][16 * 72];
    __shared__ float bn1l[64], bn2l[64];

    const int t = threadIdx.x;
    stage_wblock(wlds[0], Wn1, t, 256);
    stage_wblock(wlds[1], Wn1 + 64 * 64, t, 256);
    stage_wblock(wlds[2], Wn2, t, 256);
    if (t < 64) { bn1l[t] = bn1[t]; bn2l[t] = bn2[t]; }
    __syncthreads();

    const int wave = t >> 6, lane = t & 63;
    const int l16 = lane & 15, lq = lane >> 4;
    const int ntile = N >> 4;
    unsigned short* ml = mlds[wave];

    for (int tile = blockIdx.x * 4 + wave; tile < ntile; tile += gridDim.x * 4) {
        const int nb = tile << 4;
        bf16x8 fH[2], fA[2];
        const f32x4* ph = reinterpret_cast<const f32x4*>(h + (size_t)(nb + l16) * 64);
        const f32x4* pa = reinterpret_cast<const f32x4*>(aggf + (size_t)(nb + l16) * 64);
#pragma unroll
        for (int ks = 0; ks < 2; ++ks) {
            fH[ks] = cvt8(ph[ks * 8 + lq * 2], ph[ks * 8 + lq * 2 + 1]);
            fA[ks] = cvt8(pa[ks * 8 + lq * 2], pa[ks * 8 + lq * 2 + 1]);
        }
        f32x4 acc[4];
#pragma unroll
        for (int nt = 0; nt < 4; ++nt) { float b = bn1l[nt * 16 + l16]; acc[nt] = (f32x4){b, b, b, b}; }
#pragma unroll
        for (int ks = 0; ks < 2; ++ks)
#pragma unroll
            for (int nt = 0; nt < 4; ++nt)
                acc[nt] = mfma16(fH[ks], ldsB(wlds[0], nt, ks, lane), acc[nt]);
#pragma unroll
        for (int ks = 0; ks < 2; ++ks)
#pragma unroll
            for (int nt = 0; nt < 4; ++nt)
                acc[nt] = mfma16(fA[ks], ldsB(wlds[1], nt, ks, lane), acc[nt]);
#pragma unroll
        for (int nt = 0; nt < 4; ++nt)
#pragma unroll
            for (int r = 0; r < 4; ++r)
                ml[(lq * 4 + r) * 72 + nt * 16 + l16] = f2b(fmaxf(acc[nt][r], 0.f));
        bf16x8 fM[2];
#pragma unroll
        for (int ks = 0; ks < 2; ++ks)
            fM[ks] = __builtin_bit_cast(bf16x8,
                *reinterpret_cast<const u16x8*>(ml + l16 * 72 + ks * 32 + lq * 8));
        f32x4 acc2[4];
#pragma unroll
        for (int nt = 0; nt < 4; ++nt) { float b = bn2l[nt * 16 + l16]; acc2[nt] = (f32x4){b, b, b, b}; }
#pragma unroll
        for (int ks = 0; ks < 2; ++ks)
#pragma unroll
            for (int nt = 0; nt < 4; ++nt)
                acc2[nt] = mfma16(fM[ks], ldsB(wlds[2], nt, ks, lane), acc2[nt]);
#pragma unroll
        for (int nt = 0; nt < 4; ++nt)
#pragma unroll
            for (int r = 0; r < 4; ++r) {
                size_t idx = (size_t)(nb + lq * 4 + r) * 64 + nt * 16 + l16;
                hout[idx] = h[idx] + acc2[nt][r];
            }
    }
}

// ---------------------------------------------------------------- helpers
__global__ void f32_to_bf16(const float* __restrict__ src, unsigned short* __restrict__ dst, int n8)
{
    int i = blockIdx.x * 256 + threadIdx.x;
    if (i < n8) {
        const f32x4* p = reinterpret_cast<const f32x4*>(src + (size_t)i * 8);
        bf16x8 v = cvt8(p[0], p[1]);
        reinterpret_cast<u16x8*>(dst)[i] = __builtin_bit_cast(u16x8, v);
    }
}

__global__ void egcl_coord(const float* __restrict__ cacc, float* __restrict__ cout, int N)
{
    int n = blockIdx.x * 256 + threadIdx.x;
    if (n < N) {
        f32x4 c = *reinterpret_cast<const f32x4*>(cacc + (size_t)n * 4);
        float inv = 1.f / fmaxf(c[3], 1.f);
        cout[n * 3 + 0] = c[0] * inv;
        cout[n * 3 + 1] = c[1] * inv;
        cout[n * 3 + 2] = c[2] * inv;
    }
}

extern "C" void kernel_launch(void* const* d_in, const int* in_sizes, int n_in,
                              void* d_out, int out_size, void* d_ws, size_t ws_size,
                              hipStream_t stream)
{
    const float* h     = (const float*)d_in[0];
    const float* coord = (const float*)d_in[1];
    const int*   eidx  = (const int*)d_in[2];
    const float* We1 = (const float*)d_in[3];  const float* be1 = (const float*)d_in[4];
    const float* We2 = (const float*)d_in[5];  const float* be2 = (const float*)d_in[6];
    const float* Wn1 = (const float*)d_in[7];  const float* bn1 = (const float*)d_in[8];
    const float* Wn2 = (const float*)d_in[9];  const float* bn2 = (const float*)d_in[10];
    const float* Wc1 = (const float*)d_in[11]; const float* bc1 = (const float*)d_in[12];
    const float* Wc2 = (const float*)d_in[13];

    const int N = in_sizes[0] / 64;
    const int E = in_sizes[2] / 2;

    float* hout = (float*)d_out;
    float* cout = hout + (size_t)N * 64;

    const int ntileN = N >> 4;
    const int nblkN  = (ntileN + 3) / 4;

    // sorted-path workspace layout
    int* cnt  = (int*)d_ws;                                   // N ints
    int* off  = (int*)((char*)d_ws + (256u << 10));           // N+1 ints
    int* woff = (int*)((char*)d_ws + (512u << 10));           // N ints
    int* scol = (int*)((char*)d_ws + (1u << 20));             // E ints
    unsigned short* hb = (unsigned short*)((char*)d_ws + (5u << 20)); // N*64 bf16

    const size_t need_sorted = (5u << 20) + (size_t)N * 128;
    const bool use_sorted = (ws_size >= need_sorted) && (N % 16 == 0) && N > 0
                            && ((size_t)E * 4 <= (4u << 20));

    if (use_sorted) {
        hipMemsetAsync(cnt, 0, (size_t)N * sizeof(int), stream);
        int n8 = N * 8;
        f32_to_bf16<<<(n8 + 255) / 256, 256, 0, stream>>>(h, hb, n8);
        k_hist<<<(E + 255) / 256, 256, 0, stream>>>(eidx, cnt, E);
        k_scan<<<1, 1024, 0, stream>>>(cnt, off, woff, N, E);
        k_scatter<<<(E + 255) / 256, 256, 0, stream>>>(eidx, eidx + E, woff, scol, E);
        const int nTe = N >> 3;
        egcl_edge_sorted<<<(nTe + 7) / 8, 512, 0, stream>>>(
            hb, coord, off, scol, We1, be1, We2, be2, Wc1, bc1, Wc2,
            hout /*aggf*/, cout, N);
        egcl_node_fb<<<nblkN, 256, 0, stream>>>(h, hout /*aggf*/,
                                                Wn1, bn1, Wn2, bn2, hout, N);
    } else {
        float* cacc = (float*)d_ws;            // N*4 floats
        float* aggf = hout;
        hipMemsetAsync(cacc, 0, (size_t)N * 4 * sizeof(float), stream);
        hipMemsetAsync(aggf, 0, (size_t)N * 64 * sizeof(float), stream);
        egcl_edge_fb<<<2048, 512, 0, stream>>>(h, coord, eidx, eidx + E,
                                               We1, be1, We2, be2, Wc1, bc1, Wc2,
                                               aggf, cacc, E);
        egcl_node_fb<<<nblkN, 256, 0, stream>>>(h, aggf, Wn1, bn1, Wn2, bn2, hout, N);
        egcl_coord<<<(N + 255) / 256, 256, 0, stream>>>(cacc, cout, N);
    }
}

// Round 2
// 620.517 us; speedup vs baseline: 1.2881x; 1.2881x over previous
//
#include <hip/hip_runtime.h>

typedef float  f32x4  __attribute__((ext_vector_type(4)));
typedef __bf16 bf16x8 __attribute__((ext_vector_type(8)));
typedef unsigned short u16x8 __attribute__((ext_vector_type(8)));
typedef unsigned int   u32x4 __attribute__((ext_vector_type(4)));

__device__ inline unsigned short f2b(float f) {
    unsigned u = __builtin_bit_cast(unsigned, f);
    u += 0x7fffu + ((u >> 16) & 1u);       // round-to-nearest-even
    return (unsigned short)(u >> 16);
}

__device__ inline unsigned pk2(float a, float b) {
    return (unsigned)f2b(a) | ((unsigned)f2b(b) << 16);
}

__device__ inline f32x4 mfma16(bf16x8 a, bf16x8 b, f32x4 c) {
    return __builtin_amdgcn_mfma_f32_16x16x32_bf16(a, b, c, 0, 0, 0);
}

__device__ inline bf16x8 cvt8(f32x4 a, f32x4 b) {
    u16x8 v;
    v[0] = f2b(a[0]); v[1] = f2b(a[1]); v[2] = f2b(a[2]); v[3] = f2b(a[3]);
    v[4] = f2b(b[0]); v[5] = f2b(b[1]); v[6] = f2b(b[2]); v[7] = f2b(b[3]);
    return __builtin_bit_cast(bf16x8, v);
}

__device__ inline bf16x8 ldsA(const unsigned short* base, int frag, int lane) {
    return __builtin_bit_cast(bf16x8,
        *reinterpret_cast<const u16x8*>(base + ((frag * 64 + lane) << 3)));
}

// ============================ CSR build ============================
__global__ void k_hist(const int* __restrict__ erow, int* __restrict__ cnt, int E)
{
    int i = blockIdx.x * 256 + threadIdx.x;
    if (i < E) atomicAdd(&cnt[erow[i]], 1);
}

// phase 1: per-block partial sums of cnt
__global__ void k_scan1(const int* __restrict__ cnt, int* __restrict__ bsum, int N)
{
    const int b = blockIdx.x, t = threadIdx.x;
    const int chunk = (N + gridDim.x - 1) / gridDim.x;
    const int lo = b * chunk;
    const int hi = min(lo + chunk, N);
    int s = 0;
    for (int i = lo + t; i < hi; i += 256) s += cnt[i];
#pragma unroll
    for (int d = 1; d < 64; d <<= 1) s += __shfl_xor(s, d, 64);
    __shared__ int ws[4];
    if ((t & 63) == 0) ws[t >> 6] = s;
    __syncthreads();
    if (t == 0) bsum[b] = ws[0] + ws[1] + ws[2] + ws[3];
}

// phase 2: exclusive scan of the 128 block sums (one block, 128 threads)
__global__ void k_scan2(int* __restrict__ bsum)
{
    __shared__ int wt[2];
    const int t = threadIdx.x;
    const int lane = t & 63;
    int v = bsum[t];
    int sc = v;
#pragma unroll
    for (int d = 1; d < 64; d <<= 1) { int u = __shfl_up(sc, d, 64); if (lane >= d) sc += u; }
    if (lane == 63) wt[t >> 6] = sc;
    __syncthreads();
    int add = (t >= 64) ? wt[0] : 0;
    bsum[t] = sc - v + add;
}

// phase 3: write per-element exclusive offsets
__global__ void k_scan3(const int* __restrict__ cnt, const int* __restrict__ bsum,
                        int* __restrict__ off, int* __restrict__ woff, int N, int E)
{
    const int b = blockIdx.x, t = threadIdx.x;
    const int chunk = (N + gridDim.x - 1) / gridDim.x;
    const int lo = b * chunk;
    const int hi = min(lo + chunk, N);
    const int tchunk = (chunk + 255) / 256;
    const int tlo = lo + t * tchunk;
    const int thi = min(tlo + tchunk, hi);
    int s = 0;
    for (int i = tlo; i < thi; ++i) s += cnt[i];
    const int lane = t & 63, wv = t >> 6;
    int sc = s;
#pragma unroll
    for (int d = 1; d < 64; d <<= 1) { int u = __shfl_up(sc, d, 64); if (lane >= d) sc += u; }
    __shared__ int ws[4];
    if (lane == 63) ws[wv] = sc;
    __syncthreads();
    int wadd = 0;
#pragma unroll
    for (int k = 0; k < 4; ++k) wadd += (k < wv) ? ws[k] : 0;
    int run = bsum[b] + wadd + (sc - s);
    for (int i = tlo; i < thi; ++i) { off[i] = run; woff[i] = run; run += cnt[i]; }
    if (b == 0 && t == 0) off[N] = E;
}

__global__ void k_scatter(const int* __restrict__ erow, const int* __restrict__ ecol,
                          int* __restrict__ woff, int* __restrict__ scol, int E)
{
    int i = blockIdx.x * 256 + threadIdx.x;
    if (i < E) {
        int pos = atomicAdd(&woff[erow[i]], 1);
        scol[pos] = ecol[i];
    }
}

// ===================== SORTED EDGE PASS (sel-matrix MFMA aggregation) ==========
// One wave owns a 16-node window of row-sorted edges. Per 16-edge group the
// edge MLP runs as before; aggregation is done by 5 extra MFMAs against a
// 16x16 0/1 selection matrix (node-of-edge) accumulating agg[64ch][16nodes]
// plus a coord tile {x,y,z,cnt} entirely in registers. One coalesced 256B
// store per node at window end. No atomics, no serial segment loop, no
// long-lived per-group state.
__global__ __launch_bounds__(256, 3) void egcl_edge_sorted(
    const unsigned short* __restrict__ hb,
    const float* __restrict__ coord,
    const int* __restrict__ off, const int* __restrict__ scol,
    const float* __restrict__ We1, const float* __restrict__ be1,
    const float* __restrict__ We2, const float* __restrict__ be2,
    const float* __restrict__ Wc1, const float* __restrict__ bc1,
    const float* __restrict__ Wc2,
    float* __restrict__ aggf, float* __restrict__ cout, int N)
{
    __shared__ __align__(16) unsigned short A1[16 * 512];
    __shared__ __align__(16) unsigned short A2[8 * 512];
    __shared__ __align__(16) unsigned short A3[8 * 512];
    __shared__ __align__(16) float bv[5][64];
    __shared__ __align__(16) unsigned stl[4][34 * 16];     // per-wave stash [cp][edge]
    __shared__ __align__(16) unsigned short hl[4][16 * 72]; // per-wave window h rows
    __shared__ __align__(16) float cl[4][64];               // per-wave window coords

    const int t = threadIdx.x;
    for (int i = t; i < 8192; i += 256) {
        int j = i & 7, lane = (i >> 3) & 63, fi = i >> 9;
        int mt = fi >> 2, ks = fi & 3;
        int in_ch = ks * 32 + ((lane >> 4) << 3) + j;
        int out   = mt * 16 + (lane & 15);
        A1[i] = f2b(We1[in_ch * 64 + out]);
    }
    for (int i = t; i < 4096; i += 256) {
        int j = i & 7, lane = (i >> 3) & 63, fi = i >> 9;
        int mt = fi >> 1, ks = fi & 1;
        int c   = (ks * 2 + (j >> 2)) * 16 + ((lane >> 4) & 3) * 4 + (j & 3);
        int out = mt * 16 + (lane & 15);
        A2[i] = f2b(We2[c * 64 + out]);
        A3[i] = f2b(Wc1[c * 64 + out]);
    }
    if (t < 64) {
        bv[0][t] = be1[t]; bv[1][t] = We1[128 * 64 + t];
        bv[2][t] = be2[t]; bv[3][t] = bc1[t]; bv[4][t] = Wc2[t];
    }
    __syncthreads();

    const int lane = t & 63;
    const int l16 = lane & 15, lq = lane >> 4;
    const int w = t >> 6;
    unsigned* st2 = stl[w];
    unsigned short* hrw = hl[w];
    float* crw = cl[w];

    const int nWin = N >> 4;
    const int window = blockIdx.x * 4 + w;
    if (window >= nWin) return;
    const int nb = window << 4;

    // ---- stage the window's 16 node rows (h) + coords into wave-private LDS
    {
        int row = lane >> 2, ck2 = (lane & 3) << 1;
#pragma unroll
        for (int j = 0; j < 2; ++j)
            *reinterpret_cast<u16x8*>(hrw + row * 72 + (ck2 + j) * 8) =
                *reinterpret_cast<const u16x8*>(hb + (size_t)(nb + row) * 64 + (ck2 + j) * 8);
    }
    crw[lane] = ((lane & 3) < 3) ? coord[(size_t)(nb + (lane >> 2)) * 3 + (lane & 3)] : 0.f;

    // window offsets -> SGPRs
    int ok[16];
#pragma unroll
    for (int k = 0; k < 16; ++k) ok[k] = __builtin_amdgcn_readfirstlane(off[nb + k]);
    const int s0 = ok[0];
    const int s1 = __builtin_amdgcn_readfirstlane(off[nb + 16]);

    // persistent accumulators: agg[0..3] = channel tiles, agg[4] = {x,y,z,cnt}
    f32x4 agg[5];
#pragma unroll
    for (int k = 0; k < 5; ++k) agg[k] = (f32x4){0.f, 0.f, 0.f, 0.f};

    if (s1 > s0) {
        const int s1m1 = s1 - 1;
        int gb = s0;
        int p  = gb + l16;

        // prologue: group 0 data + group 1 indices
        int pm = (p < s1m1) ? p : s1m1;
        int c0 = scol[pm];
        u16x8 hc0, hc1;
        {
            const u16x8* hp = reinterpret_cast<const u16x8*>(hb + (size_t)c0 * 64);
            hc0 = hp[lq]; hc1 = hp[4 + lq];
        }
        float cpx = 0.f, cpy = 0.f, cpz = 0.f;
        if (lq == 1) { const float* pp = coord + (size_t)c0 * 3; cpx = pp[0]; cpy = pp[1]; cpz = pp[2]; }
        int q1 = gb + 16 + l16;
        int c1 = scol[(q1 < s1m1) ? q1 : s1m1];

        const int nG = (s1 - s0 + 15) >> 4;
        for (int g = 0; g < nG; ++g) {
            // ---- stage next group's data
            u16x8 nh0, nh1;
            {
                const u16x8* np = reinterpret_cast<const u16x8*>(hb + (size_t)c1 * 64);
                nh0 = np[lq]; nh1 = np[4 + lq];
            }
            float nx = 0.f, ny = 0.f, nz = 0.f;
            if (lq == 1) { const float* pp = coord + (size_t)c1 * 3; nx = pp[0]; ny = pp[1]; nz = pp[2]; }
            int q2 = gb + 32 + l16;
            int c2 = scol[(q2 < s1m1) ? q2 : s1m1];

            // ---- node index within window for this lane's edge
            int ni = 0;
#pragma unroll
            for (int k = 1; k < 16; ++k) ni += (p >= ok[k]) ? 1 : 0;

            // ---- operands
            bf16x8 bR[2];
            bR[0] = __builtin_bit_cast(bf16x8,
                    *reinterpret_cast<const u16x8*>(hrw + ni * 72 + lq * 8));
            bR[1] = __builtin_bit_cast(bf16x8,
                    *reinterpret_cast<const u16x8*>(hrw + ni * 72 + (4 + lq) * 8));
            bf16x8 bC[2] = { __builtin_bit_cast(bf16x8, hc0), __builtin_bit_cast(bf16x8, hc1) };

            float prx = crw[ni * 4 + 0], pry = crw[ni * 4 + 1], prz = crw[ni * 4 + 2];
            float pcx = __shfl(cpx, 16 + l16, 64);
            float pcy = __shfl(cpy, 16 + l16, 64);
            float pcz = __shfl(cpz, 16 + l16, 64);
            float dx = prx - pcx, dy = pry - pcy, dz = prz - pcz;
            float rad = dx * dx + dy * dy + dz * dz;

            // ---- layer 1
            f32x4 a1[4];
#pragma unroll
            for (int mt = 0; mt < 4; ++mt)
                a1[mt] = *reinterpret_cast<const f32x4*>(&bv[0][mt * 16 + lq * 4]);
#pragma unroll
            for (int ks = 0; ks < 2; ++ks)
#pragma unroll
                for (int mt = 0; mt < 4; ++mt)
                    a1[mt] = mfma16(ldsA(A1, mt * 4 + ks, lane), bR[ks], a1[mt]);
#pragma unroll
            for (int ks = 0; ks < 2; ++ks)
#pragma unroll
                for (int mt = 0; mt < 4; ++mt)
                    a1[mt] = mfma16(ldsA(A1, mt * 4 + 2 + ks, lane), bC[ks], a1[mt]);
#pragma unroll
            for (int mt = 0; mt < 4; ++mt) {
                f32x4 wv = *reinterpret_cast<const f32x4*>(&bv[1][mt * 16 + lq * 4]);
#pragma unroll
                for (int rr = 0; rr < 4; ++rr)
                    a1[mt][rr] = fmaxf(a1[mt][rr] + rad * wv[rr], 0.f);
            }

            // ---- layer 2
            bf16x8 b2[2] = { cvt8(a1[0], a1[1]), cvt8(a1[2], a1[3]) };
            f32x4 a2[4];
#pragma unroll
            for (int mt = 0; mt < 4; ++mt)
                a2[mt] = *reinterpret_cast<const f32x4*>(&bv[2][mt * 16 + lq * 4]);
#pragma unroll
            for (int ks = 0; ks < 2; ++ks)
#pragma unroll
                for (int mt = 0; mt < 4; ++mt)
                    a2[mt] = mfma16(ldsA(A2, mt * 2 + ks, lane), b2[ks], a2[mt]);
#pragma unroll
            for (int mt = 0; mt < 4; ++mt)
#pragma unroll
                for (int rr = 0; rr < 4; ++rr)
                    a2[mt][rr] = fmaxf(a2[mt][rr], 0.f);

            // ---- stash a2 (channel-pair major): st2[cp][e], cp = mt*8+lq*2+b
#pragma unroll
            for (int mt = 0; mt < 4; ++mt) {
                st2[(mt * 8 + lq * 2 + 0) * 16 + l16] = pk2(a2[mt][0], a2[mt][1]);
                st2[(mt * 8 + lq * 2 + 1) * 16 + l16] = pk2(a2[mt][2], a2[mt][3]);
            }

            // ---- gate (MFMAs overlap the stash writes)
            bf16x8 b3[2] = { cvt8(a2[0], a2[1]), cvt8(a2[2], a2[3]) };
            f32x4 a3[4];
#pragma unroll
            for (int mt = 0; mt < 4; ++mt)
                a3[mt] = *reinterpret_cast<const f32x4*>(&bv[3][mt * 16 + lq * 4]);
#pragma unroll
            for (int ks = 0; ks < 2; ++ks)
#pragma unroll
                for (int mt = 0; mt < 4; ++mt)
                    a3[mt] = mfma16(ldsA(A3, mt * 2 + ks, lane), b3[ks], a3[mt]);
            float gg = 0.f;
#pragma unroll
            for (int mt = 0; mt < 4; ++mt) {
                f32x4 wv = *reinterpret_cast<const f32x4*>(&bv[4][mt * 16 + lq * 4]);
#pragma unroll
                for (int rr = 0; rr < 4; ++rr)
                    gg += fmaxf(a3[mt][rr], 0.f) * wv[rr];
            }
            gg += __shfl_xor(gg, 16, 64);
            gg += __shfl_xor(gg, 32, 64);

            float dsel = (lq == 0) ? dx : (lq == 1) ? dy : dz;
            float val  = fminf(fmaxf(dsel * gg, -100.f), 100.f);

            // ---- coord stash rows {x,y},{z,1}: slots cp=32,33
            float vy = __shfl(val, 16 + l16, 64);      // y from lq==1 lane (pre-branch)
            if (lq == 0) st2[32 * 16 + l16] = pk2(val, vy);
            if (lq == 2) st2[33 * 16 + l16] = pk2(val, 1.0f);

            // ---- selection fragment: sel[k][n] = (node(edge k)==n && in-range)
            u16x8 sv;
#pragma unroll
            for (int j = 0; j < 8; ++j) {
                int ks = lq * 8 + j;
                int nik = __shfl(ni, ks & 15, 64);
                sv[j] = (ks < 16 && (gb + ks) < s1 && nik == l16)
                        ? (unsigned short)0x3F80 : (unsigned short)0;
            }
            bf16x8 self = __builtin_bit_cast(bf16x8, sv);

            // ---- A-fragments from stash + 5 accumulate MFMAs
            const int elo = (lq & 1) << 3;
#pragma unroll
            for (int tt = 0; tt < 5; ++tt) {
                int cpb = (tt < 4) ? (tt * 8 + (l16 >> 1)) : (32 + ((l16 >> 1) & 1));
                u32x4 wa = *reinterpret_cast<const u32x4*>(st2 + cpb * 16 + elo);
                u32x4 wb = *reinterpret_cast<const u32x4*>(st2 + cpb * 16 + elo + 4);
                u16x8 av;
#pragma unroll
                for (int j = 0; j < 4; ++j) {
                    av[j]     = (l16 & 1) ? (unsigned short)(wa[j] >> 16)
                                          : (unsigned short)(wa[j] & 0xffffu);
                    av[4 + j] = (l16 & 1) ? (unsigned short)(wb[j] >> 16)
                                          : (unsigned short)(wb[j] & 0xffffu);
                }
                agg[tt] = mfma16(__builtin_bit_cast(bf16x8, av), self, agg[tt]);
            }

            // ---- rotate
            gb += 16; p += 16;
            c1 = c2;
            hc0 = nh0; hc1 = nh1;
            cpx = nx; cpy = ny; cpz = nz;
        }
    }

    // ---- window stores: agg tiles (D: col=node l16, row=ch lq*4+rr)
#pragma unroll
    for (int mt = 0; mt < 4; ++mt)
        *reinterpret_cast<f32x4*>(aggf + (size_t)(nb + l16) * 64 + mt * 16 + lq * 4) = agg[mt];
    if (lq == 0) {
        float inv = 1.f / fmaxf(agg[4][3], 1.f);
        cout[(size_t)(nb + l16) * 3 + 0] = agg[4][0] * inv;
        cout[(size_t)(nb + l16) * 3 + 1] = agg[4][1] * inv;
        cout[(size_t)(nb + l16) * 3 + 2] = agg[4][2] * inv;
    }
}

// ===================== FALLBACK EDGE PASS (atomic, f32) =====================
__global__ __launch_bounds__(512, 4) void egcl_edge_fb(
    const float* __restrict__ h, const float* __restrict__ coord,
    const int* __restrict__ erow, const int* __restrict__ ecol,
    const float* __restrict__ We1, const float* __restrict__ be1,
    const float* __restrict__ We2, const float* __restrict__ be2,
    const float* __restrict__ Wc1, const float* __restrict__ bc1,
    const float* __restrict__ Wc2,
    float* __restrict__ aggf, float* __restrict__ cacc, int E)
{
    __shared__ __align__(16) unsigned short A1[16 * 512];
    __shared__ __align__(16) unsigned short A2[8 * 512];
    __shared__ __align__(16) unsigned short A3[8 * 512];
    __shared__ __align__(16) float bv[5][64];

    const int t = threadIdx.x;
    for (int i = t; i < 8192; i += 512) {
        int j = i & 7, lane = (i >> 3) & 63, fi = i >> 9;
        int mt = fi >> 2, ks = fi & 3;
        int in_ch = ks * 32 + ((lane >> 4) << 3) + j;
        int out   = mt * 16 + (lane & 15);
        A1[i] = f2b(We1[in_ch * 64 + out]);
    }
    for (int i = t; i < 4096; i += 512) {
        int j = i & 7, lane = (i >> 3) & 63, fi = i >> 9;
        int mt = fi >> 1, ks = fi & 1;
        int c   = (ks * 2 + (j >> 2)) * 16 + ((lane >> 4) & 3) * 4 + (j & 3);
        int out = mt * 16 + (lane & 15);
        A2[i] = f2b(We2[c * 64 + out]);
        A3[i] = f2b(Wc1[c * 64 + out]);
    }
    if (t < 64) {
        bv[0][t] = be1[t]; bv[1][t] = We1[128 * 64 + t];
        bv[2][t] = be2[t]; bv[3][t] = bc1[t]; bv[4][t] = Wc2[t];
    }
    __syncthreads();

    const int lane = t & 63;
    const int l16 = lane & 15, lq = lane >> 4;
    const int stride = gridDim.x * 8;
    const int wid = (blockIdx.x << 3) + (t >> 6);
    const int ntile = E >> 4;

    for (int tile = wid; tile < ntile; tile += stride) {
        const int e = (tile << 4) + l16;
        const int r = erow[e], c = ecol[e];
        const float* pr = coord + (size_t)r * 3;
        const float* pc = coord + (size_t)c * 3;
        float dx = pr[0] - pc[0], dy = pr[1] - pc[1], dz = pr[2] - pc[2];
        float rad = dx * dx + dy * dy + dz * dz;
        const f32x4* hr = reinterpret_cast<const f32x4*>(h + (size_t)r * 64);
        const f32x4* hc = reinterpret_cast<const f32x4*>(h + (size_t)c * 64);
        bf16x8 bR[2], bC[2];
#pragma unroll
        for (int ks = 0; ks < 2; ++ks) {
            bR[ks] = cvt8(hr[ks * 8 + lq * 2], hr[ks * 8 + lq * 2 + 1]);
            bC[ks] = cvt8(hc[ks * 8 + lq * 2], hc[ks * 8 + lq * 2 + 1]);
        }
        f32x4 a1[4];
#pragma unroll
        for (int mt = 0; mt < 4; ++mt)
            a1[mt] = *reinterpret_cast<const f32x4*>(&bv[0][mt * 16 + lq * 4]);
#pragma unroll
        for (int ks = 0; ks < 2; ++ks)
#pragma unroll
            for (int mt = 0; mt < 4; ++mt)
                a1[mt] = mfma16(ldsA(A1, mt * 4 + ks, lane), bR[ks], a1[mt]);
#pragma unroll
        for (int ks = 0; ks < 2; ++ks)
#pragma unroll
            for (int mt = 0; mt < 4; ++mt)
                a1[mt] = mfma16(ldsA(A1, mt * 4 + 2 + ks, lane), bC[ks], a1[mt]);
#pragma unroll
        for (int mt = 0; mt < 4; ++mt) {
            f32x4 wv = *reinterpret_cast<const f32x4*>(&bv[1][mt * 16 + lq * 4]);
#pragma unroll
            for (int rr = 0; rr < 4; ++rr)
                a1[mt][rr] = fmaxf(a1[mt][rr] + rad * wv[rr], 0.f);
        }
        bf16x8 b2[2] = { cvt8(a1[0], a1[1]), cvt8(a1[2], a1[3]) };
        f32x4 a2[4];
#pragma unroll
        for (int mt = 0; mt < 4; ++mt)
            a2[mt] = *reinterpret_cast<const f32x4*>(&bv[2][mt * 16 + lq * 4]);
#pragma unroll
        for (int ks = 0; ks < 2; ++ks)
#pragma unroll
            for (int mt = 0; mt < 4; ++mt)
                a2[mt] = mfma16(ldsA(A2, mt * 2 + ks, lane), b2[ks], a2[mt]);
#pragma unroll
        for (int mt = 0; mt < 4; ++mt)
#pragma unroll
            for (int rr = 0; rr < 4; ++rr) {
                a2[mt][rr] = fmaxf(a2[mt][rr], 0.f);
                atomicAdd(&aggf[(size_t)r * 64 + mt * 16 + lq * 4 + rr], a2[mt][rr]);
            }
        bf16x8 b3[2] = { cvt8(a2[0], a2[1]), cvt8(a2[2], a2[3]) };
        f32x4 a3[4];
#pragma unroll
        for (int mt = 0; mt < 4; ++mt)
            a3[mt] = *reinterpret_cast<const f32x4*>(&bv[3][mt * 16 + lq * 4]);
#pragma unroll
        for (int ks = 0; ks < 2; ++ks)
#pragma unroll
            for (int mt = 0; mt < 4; ++mt)
                a3[mt] = mfma16(ldsA(A3, mt * 2 + ks, lane), b3[ks], a3[mt]);
        float gg = 0.f;
#pragma unroll
        for (int mt = 0; mt < 4; ++mt) {
            f32x4 wv = *reinterpret_cast<const f32x4*>(&bv[4][mt * 16 + lq * 4]);
#pragma unroll
            for (int rr = 0; rr < 4; ++rr)
                gg += fmaxf(a3[mt][rr], 0.f) * wv[rr];
        }
        gg += __shfl_xor(gg, 16, 64);
        gg += __shfl_xor(gg, 32, 64);
        float dsel = (lq == 0) ? dx : (lq == 1) ? dy : dz;
        float val  = (lq == 3) ? 1.0f : fminf(fmaxf(dsel * gg, -100.f), 100.f);
        atomicAdd(&cacc[(size_t)r * 4 + lq], val);
    }
}

// ============================== NODE PASS ==============================
__device__ inline void stage_wblock(unsigned short* dst, const float* src, int t, int nthr) {
    for (int i = t; i < 4096; i += nthr) {
        int k = i >> 6, n = i & 63;
        int pos = (((n >> 4) * 2 + (k >> 5)) * 64 + ((((k >> 3) & 3) << 4) | (n & 15))) * 8 + (k & 7);
        dst[pos] = f2b(src[i]);
    }
}

__device__ inline bf16x8 ldsB(const unsigned short* base, int nt, int ks, int lane) {
    return __builtin_bit_cast(bf16x8,
        *reinterpret_cast<const u16x8*>(base + (((nt * 2 + ks) * 64 + lane) << 3)));
}

__global__ __launch_bounds__(256) void egcl_node_fb(
    const float* __restrict__ h, const float* __restrict__ aggf,
    const float* __restrict__ Wn1, const float* __restrict__ bn1,
    const float* __restrict__ Wn2, const float* __restrict__ bn2,
    float* __restrict__ hout, int N)
{
    __shared__ __align__(16) unsigned short wlds[3][4096];
    __shared__ __align__(16) unsigned short mlds[4][16 * 72];
    __shared__ float bn1l[64], bn2l[64];

    const int t = threadIdx.x;
    stage_wblock(wlds[0], Wn1, t, 256);
    stage_wblock(wlds[1], Wn1 + 64 * 64, t, 256);
    stage_wblock(wlds[2], Wn2, t, 256);
    if (t < 64) { bn1l[t] = bn1[t]; bn2l[t] = bn2[t]; }
    __syncthreads();

    const int wave = t >> 6, lane = t & 63;
    const int l16 = lane & 15, lq = lane >> 4;
    const int ntile = N >> 4;
    unsigned short* ml = mlds[wave];

    for (int tile = blockIdx.x * 4 + wave; tile < ntile; tile += gridDim.x * 4) {
        const int nb = tile << 4;
        bf16x8 fH[2], fA[2];
        const f32x4* ph = reinterpret_cast<const f32x4*>(h + (size_t)(nb + l16) * 64);
        const f32x4* pa = reinterpret_cast<const f32x4*>(aggf + (size_t)(nb + l16) * 64);
#pragma unroll
        for (int ks = 0; ks < 2; ++ks) {
            fH[ks] = cvt8(ph[ks * 8 + lq * 2], ph[ks * 8 + lq * 2 + 1]);
            fA[ks] = cvt8(pa[ks * 8 + lq * 2], pa[ks * 8 + lq * 2 + 1]);
        }
        f32x4 acc[4];
#pragma unroll
        for (int nt = 0; nt < 4; ++nt) { float b = bn1l[nt * 16 + l16]; acc[nt] = (f32x4){b, b, b, b}; }
#pragma unroll
        for (int ks = 0; ks < 2; ++ks)
#pragma unroll
            for (int nt = 0; nt < 4; ++nt)
                acc[nt] = mfma16(fH[ks], ldsB(wlds[0], nt, ks, lane), acc[nt]);
#pragma unroll
        for (int ks = 0; ks < 2; ++ks)
#pragma unroll
            for (int nt = 0; nt < 4; ++nt)
                acc[nt] = mfma16(fA[ks], ldsB(wlds[1], nt, ks, lane), acc[nt]);
#pragma unroll
        for (int nt = 0; nt < 4; ++nt)
#pragma unroll
            for (int r = 0; r < 4; ++r)
                ml[(lq * 4 + r) * 72 + nt * 16 + l16] = f2b(fmaxf(acc[nt][r], 0.f));
        bf16x8 fM[2];
#pragma unroll
        for (int ks = 0; ks < 2; ++ks)
            fM[ks] = __builtin_bit_cast(bf16x8,
                *reinterpret_cast<const u16x8*>(ml + l16 * 72 + ks * 32 + lq * 8));
        f32x4 acc2[4];
#pragma unroll
        for (int nt = 0; nt < 4; ++nt) { float b = bn2l[nt * 16 + l16]; acc2[nt] = (f32x4){b, b, b, b}; }
#pragma unroll
        for (int ks = 0; ks < 2; ++ks)
#pragma unroll
            for (int nt = 0; nt < 4; ++nt)
                acc2[nt] = mfma16(fM[ks], ldsB(wlds[2], nt, ks, lane), acc2[nt]);
#pragma unroll
        for (int nt = 0; nt < 4; ++nt)
#pragma unroll
            for (int r = 0; r < 4; ++r) {
                size_t idx = (size_t)(nb + lq * 4 + r) * 64 + nt * 16 + l16;
                hout[idx] = h[idx] + acc2[nt][r];
            }
    }
}

// ---------------------------------------------------------------- helpers
__global__ void f32_to_bf16(const float* __restrict__ src, unsigned short* __restrict__ dst, int n8)
{
    int i = blockIdx.x * 256 + threadIdx.x;
    if (i < n8) {
        const f32x4* p = reinterpret_cast<const f32x4*>(src + (size_t)i * 8);
        bf16x8 v = cvt8(p[0], p[1]);
        reinterpret_cast<u16x8*>(dst)[i] = __builtin_bit_cast(u16x8, v);
    }
}

__global__ void egcl_coord(const float* __restrict__ cacc, float* __restrict__ cout, int N)
{
    int n = blockIdx.x * 256 + threadIdx.x;
    if (n < N) {
        f32x4 c = *reinterpret_cast<const f32x4*>(cacc + (size_t)n * 4);
        float inv = 1.f / fmaxf(c[3], 1.f);
        cout[n * 3 + 0] = c[0] * inv;
        cout[n * 3 + 1] = c[1] * inv;
        cout[n * 3 + 2] = c[2] * inv;
    }
}

extern "C" void kernel_launch(void* const* d_in, const int* in_sizes, int n_in,
                              void* d_out, int out_size, void* d_ws, size_t ws_size,
                              hipStream_t stream)
{
    const float* h     = (const float*)d_in[0];
    const float* coord = (const float*)d_in[1];
    const int*   eidx  = (const int*)d_in[2];
    const float* We1 = (const float*)d_in[3];  const float* be1 = (const float*)d_in[4];
    const float* We2 = (const float*)d_in[5];  const float* be2 = (const float*)d_in[6];
    const float* Wn1 = (const float*)d_in[7];  const float* bn1 = (const float*)d_in[8];
    const float* Wn2 = (const float*)d_in[9];  const float* bn2 = (const float*)d_in[10];
    const float* Wc1 = (const float*)d_in[11]; const float* bc1 = (const float*)d_in[12];
    const float* Wc2 = (const float*)d_in[13];

    const int N = in_sizes[0] / 64;
    const int E = in_sizes[2] / 2;

    float* hout = (float*)d_out;
    float* cout = hout + (size_t)N * 64;

    const int ntileN = N >> 4;
    const int nblkN  = (ntileN + 3) / 4;

    // sorted-path workspace layout
    int* cnt  = (int*)d_ws;                                   // N ints
    int* off  = (int*)((char*)d_ws + (256u << 10));           // N+1 ints
    int* woff = (int*)((char*)d_ws + (512u << 10));           // N ints
    int* bsum = (int*)((char*)d_ws + (768u << 10));           // 128 ints
    int* scol = (int*)((char*)d_ws + (1u << 20));             // E ints
    unsigned short* hb = (unsigned short*)((char*)d_ws + (5u << 20)); // N*64 bf16

    const size_t need_sorted = (5u << 20) + (size_t)N * 128;
    const bool use_sorted = (ws_size >= need_sorted) && (N % 16 == 0) && N > 0
                            && ((size_t)E * 4 <= (4u << 20));

    if (use_sorted) {
        hipMemsetAsync(cnt, 0, (size_t)N * sizeof(int), stream);
        int n8 = N * 8;
        f32_to_bf16<<<(n8 + 255) / 256, 256, 0, stream>>>(h, hb, n8);
        k_hist<<<(E + 255) / 256, 256, 0, stream>>>(eidx, cnt, E);
        k_scan1<<<128, 256, 0, stream>>>(cnt, bsum, N);
        k_scan2<<<1, 128, 0, stream>>>(bsum);
        k_scan3<<<128, 256, 0, stream>>>(cnt, bsum, off, woff, N, E);
        k_scatter<<<(E + 255) / 256, 256, 0, stream>>>(eidx, eidx + E, woff, scol, E);
        const int nWin = N >> 4;
        egcl_edge_sorted<<<(nWin + 3) / 4, 256, 0, stream>>>(
            hb, coord, off, scol, We1, be1, We2, be2, Wc1, bc1, Wc2,
            hout /*aggf*/, cout, N);
        egcl_node_fb<<<nblkN, 256, 0, stream>>>(h, hout /*aggf*/,
                                                Wn1, bn1, Wn2, bn2, hout, N);
    } else {
        float* cacc = (float*)d_ws;            // N*4 floats
        float* aggf = hout;
        hipMemsetAsync(cacc, 0, (size_t)N * 4 * sizeof(float), stream);
        hipMemsetAsync(aggf, 0, (size_t)N * 64 * sizeof(float), stream);
        egcl_edge_fb<<<2048, 512, 0, stream>>>(h, coord, eidx, eidx + E,
                                               We1, be1, We2, be2, Wc1, bc1, Wc2,
                                               aggf, cacc, E);
        egcl_node_fb<<<nblkN, 256, 0, stream>>>(h, aggf, Wn1, bn1, Wn2, bn2, hout, N);
        egcl_coord<<<(N + 255) / 256, 256, 0, stream>>>(cacc, cout, N);
    }
}

// Round 3
// 385.203 us; speedup vs baseline: 2.0750x; 1.6109x over previous
//
#include <hip/hip_runtime.h>

typedef float  f32x4  __attribute__((ext_vector_type(4)));
typedef __bf16 bf16x8 __attribute__((ext_vector_type(8)));
typedef unsigned short u16x8 __attribute__((ext_vector_type(8)));
typedef unsigned int   u32x4 __attribute__((ext_vector_type(4)));

__device__ inline unsigned short f2b(float f) {
    unsigned u = __builtin_bit_cast(unsigned, f);
    u += 0x7fffu + ((u >> 16) & 1u);       // round-to-nearest-even
    return (unsigned short)(u >> 16);
}

__device__ inline unsigned pk2(float a, float b) {
    return (unsigned)f2b(a) | ((unsigned)f2b(b) << 16);
}

__device__ inline f32x4 mfma16(bf16x8 a, bf16x8 b, f32x4 c) {
    return __builtin_amdgcn_mfma_f32_16x16x32_bf16(a, b, c, 0, 0, 0);
}

__device__ inline bf16x8 cvt8(f32x4 a, f32x4 b) {
    u16x8 v;
    v[0] = f2b(a[0]); v[1] = f2b(a[1]); v[2] = f2b(a[2]); v[3] = f2b(a[3]);
    v[4] = f2b(b[0]); v[5] = f2b(b[1]); v[6] = f2b(b[2]); v[7] = f2b(b[3]);
    return __builtin_bit_cast(bf16x8, v);
}

__device__ inline bf16x8 ldsA(const unsigned short* base, int frag, int lane) {
    return __builtin_bit_cast(bf16x8,
        *reinterpret_cast<const u16x8*>(base + ((frag * 64 + lane) << 3)));
}

// ============================ CSR build ============================
__global__ void k_hist(const int* __restrict__ erow, int* __restrict__ cnt, int E)
{
    int i = blockIdx.x * 256 + threadIdx.x;
    if (i < E) atomicAdd(&cnt[erow[i]], 1);
}

// phase 1: per-block partial sums of cnt
__global__ void k_scan1(const int* __restrict__ cnt, int* __restrict__ bsum, int N)
{
    const int b = blockIdx.x, t = threadIdx.x;
    const int chunk = (N + gridDim.x - 1) / gridDim.x;
    const int lo = b * chunk;
    const int hi = min(lo + chunk, N);
    int s = 0;
    for (int i = lo + t; i < hi; i += 256) s += cnt[i];
#pragma unroll
    for (int d = 1; d < 64; d <<= 1) s += __shfl_xor(s, d, 64);
    __shared__ int ws[4];
    if ((t & 63) == 0) ws[t >> 6] = s;
    __syncthreads();
    if (t == 0) bsum[b] = ws[0] + ws[1] + ws[2] + ws[3];
}

// phase 2: exclusive scan of the 128 block sums (one block, 128 threads)
__global__ void k_scan2(int* __restrict__ bsum)
{
    __shared__ int wt[2];
    const int t = threadIdx.x;
    const int lane = t & 63;
    int v = bsum[t];
    int sc = v;
#pragma unroll
    for (int d = 1; d < 64; d <<= 1) { int u = __shfl_up(sc, d, 64); if (lane >= d) sc += u; }
    if (lane == 63) wt[t >> 6] = sc;
    __syncthreads();
    int add = (t >= 64) ? wt[0] : 0;
    bsum[t] = sc - v + add;
}

// phase 3: write per-element exclusive offsets
__global__ void k_scan3(const int* __restrict__ cnt, const int* __restrict__ bsum,
                        int* __restrict__ off, int* __restrict__ woff, int N, int E)
{
    const int b = blockIdx.x, t = threadIdx.x;
    const int chunk = (N + gridDim.x - 1) / gridDim.x;
    const int lo = b * chunk;
    const int hi = min(lo + chunk, N);
    const int tchunk = (chunk + 255) / 256;
    const int tlo = lo + t * tchunk;
    const int thi = min(tlo + tchunk, hi);
    int s = 0;
    for (int i = tlo; i < thi; ++i) s += cnt[i];
    const int lane = t & 63, wv = t >> 6;
    int sc = s;
#pragma unroll
    for (int d = 1; d < 64; d <<= 1) { int u = __shfl_up(sc, d, 64); if (lane >= d) sc += u; }
    __shared__ int ws[4];
    if (lane == 63) ws[wv] = sc;
    __syncthreads();
    int wadd = 0;
#pragma unroll
    for (int k = 0; k < 4; ++k) wadd += (k < wv) ? ws[k] : 0;
    int run = bsum[b] + wadd + (sc - s);
    for (int i = tlo; i < thi; ++i) { off[i] = run; woff[i] = run; run += cnt[i]; }
    if (b == 0 && t == 0) off[N] = E;
}

// scatter edges into row-sorted order; pack (row,col) into one u32 (N <= 65536)
__global__ void k_scatter(const int* __restrict__ erow, const int* __restrict__ ecol,
                          int* __restrict__ woff, unsigned* __restrict__ spack, int E)
{
    int i = blockIdx.x * 256 + threadIdx.x;
    if (i < E) {
        int r = erow[i];
        int pos = atomicAdd(&woff[r], 1);
        spack[pos] = (unsigned)r | ((unsigned)ecol[i] << 16);
    }
}

// ========== SORTED EDGE PASS: R0 grid-stride pipeline + per-tile partial =====
// Edges processed in row-sorted order with the round-0 double-prefetch tile
// pipeline (dense spack index loads; h/coord gathers identical in structure).
// Within each 16-edge tile, edges of one node are contiguous: the sel-matrix
// MFMA (sel[e][s] = row(e)==row(s)) reduces the tile to per-node partial sums
// in registers; only run-leader lanes scatter (f32 atomics), cutting lane-
// atomics ~4.7x vs round 0 and upgrading agg accumulation to f32.
__global__ __launch_bounds__(512, 2) void egcl_edge_srt(
    const unsigned short* __restrict__ hb,
    const float* __restrict__ coord,
    const unsigned* __restrict__ spack,
    const float* __restrict__ We1, const float* __restrict__ be1,
    const float* __restrict__ We2, const float* __restrict__ be2,
    const float* __restrict__ Wc1, const float* __restrict__ bc1,
    const float* __restrict__ Wc2,
    float* __restrict__ aggf, float* __restrict__ cacc, int E)
{
    __shared__ __align__(16) unsigned short A1[16 * 512];
    __shared__ __align__(16) unsigned short A2[8 * 512];
    __shared__ __align__(16) unsigned short A3[8 * 512];
    __shared__ __align__(16) float bv[5][64];
    __shared__ __align__(16) unsigned stl[8][34 * 16];   // per-wave stash [cp][edge]

    const int t = threadIdx.x;
    for (int i = t; i < 8192; i += 512) {
        int j = i & 7, lane = (i >> 3) & 63, fi = i >> 9;
        int mt = fi >> 2, ks = fi & 3;
        int in_ch = ks * 32 + ((lane >> 4) << 3) + j;
        int out   = mt * 16 + (lane & 15);
        A1[i] = f2b(We1[in_ch * 64 + out]);
    }
    for (int i = t; i < 4096; i += 512) {
        int j = i & 7, lane = (i >> 3) & 63, fi = i >> 9;
        int mt = fi >> 1, ks = fi & 1;
        int c   = (ks * 2 + (j >> 2)) * 16 + ((lane >> 4) & 3) * 4 + (j & 3);
        int out = mt * 16 + (lane & 15);
        A2[i] = f2b(We2[c * 64 + out]);
        A3[i] = f2b(Wc1[c * 64 + out]);
    }
    if (t < 64) {
        bv[0][t] = be1[t]; bv[1][t] = We1[128 * 64 + t];
        bv[2][t] = be2[t]; bv[3][t] = bc1[t]; bv[4][t] = Wc2[t];
    }
    __syncthreads();

    const int lane = t & 63;
    const int l16 = lane & 15, lq = lane >> 4;
    const int stride = gridDim.x * 8;
    const int wid = (blockIdx.x << 3) + (t >> 6);
    const int ntile = E >> 4;
    const int last = ntile - 1;
    unsigned* st = stl[t >> 6];

    int tile = wid;
    if (tile >= ntile) return;

    // ---------------- prologue: tile 0 data + tile 1 indices
    int eC = (tile << 4) + l16;
    unsigned pC = spack[eC];
    int rC = (int)(pC & 0xffffu), cC = (int)(pC >> 16);
    u16x8 hr0, hr1, hc0, hc1;
    {
        const u16x8* hr = reinterpret_cast<const u16x8*>(hb + (size_t)rC * 64);
        const u16x8* hc = reinterpret_cast<const u16x8*>(hb + (size_t)cC * 64);
        hr0 = hr[lq]; hr1 = hr[4 + lq]; hc0 = hc[lq]; hc1 = hc[4 + lq];
    }
    float px = 0.f, py = 0.f, pz = 0.f;
    if (lq < 2) {
        int node = (lq == 0) ? rC : cC;
        const float* pp = coord + (size_t)node * 3;
        px = pp[0]; py = pp[1]; pz = pp[2];
    }
    int t1 = tile + stride;
    int tn = (t1 < ntile) ? t1 : last;
    unsigned pN = spack[(tn << 4) + l16];
    int rN = (int)(pN & 0xffffu), cN = (int)(pN >> 16);

    for (; tile < ntile; ) {
        // ---- stage 1: issue next tile's h/coord loads
        u16x8 nr0, nr1, nc0, nc1;
        {
            const u16x8* hr = reinterpret_cast<const u16x8*>(hb + (size_t)rN * 64);
            const u16x8* hc = reinterpret_cast<const u16x8*>(hb + (size_t)cN * 64);
            nr0 = hr[lq]; nr1 = hr[4 + lq]; nc0 = hc[lq]; nc1 = hc[4 + lq];
        }
        float npx = 0.f, npy = 0.f, npz = 0.f;
        if (lq < 2) {
            int node = (lq == 0) ? rN : cN;
            const float* pp = coord + (size_t)node * 3;
            npx = pp[0]; npy = pp[1]; npz = pp[2];
        }
        // ---- stage 2: issue tile+2 index loads
        int t2 = tile + 2 * stride;
        int t2c = (t2 < ntile) ? t2 : last;
        unsigned pNN = spack[(t2c << 4) + l16];
        int rNN = (int)(pNN & 0xffffu), cNN = (int)(pNN >> 16);

        // ---- stage 3: compute current tile
        float prx = __shfl(px, l16, 64), pry = __shfl(py, l16, 64), prz = __shfl(pz, l16, 64);
        float pcx = __shfl(px, 16 + l16, 64), pcy = __shfl(py, 16 + l16, 64), pcz = __shfl(pz, 16 + l16, 64);
        float dx = prx - pcx, dy = pry - pcy, dz = prz - pcz;
        float rad = dx * dx + dy * dy + dz * dz;

        bf16x8 bR[2] = { __builtin_bit_cast(bf16x8, hr0), __builtin_bit_cast(bf16x8, hr1) };
        bf16x8 bC[2] = { __builtin_bit_cast(bf16x8, hc0), __builtin_bit_cast(bf16x8, hc1) };

        // layer 1
        f32x4 a1[4];
#pragma unroll
        for (int mt = 0; mt < 4; ++mt)
            a1[mt] = *reinterpret_cast<const f32x4*>(&bv[0][mt * 16 + lq * 4]);
#pragma unroll
        for (int ks = 0; ks < 2; ++ks)
#pragma unroll
            for (int mt = 0; mt < 4; ++mt)
                a1[mt] = mfma16(ldsA(A1, mt * 4 + ks, lane), bR[ks], a1[mt]);
#pragma unroll
        for (int ks = 0; ks < 2; ++ks)
#pragma unroll
            for (int mt = 0; mt < 4; ++mt)
                a1[mt] = mfma16(ldsA(A1, mt * 4 + 2 + ks, lane), bC[ks], a1[mt]);
#pragma unroll
        for (int mt = 0; mt < 4; ++mt) {
            f32x4 wv = *reinterpret_cast<const f32x4*>(&bv[1][mt * 16 + lq * 4]);
#pragma unroll
            for (int rr = 0; rr < 4; ++rr)
                a1[mt][rr] = fmaxf(a1[mt][rr] + rad * wv[rr], 0.f);
        }

        // layer 2
        bf16x8 b2[2] = { cvt8(a1[0], a1[1]), cvt8(a1[2], a1[3]) };
        f32x4 a2[4];
#pragma unroll
        for (int mt = 0; mt < 4; ++mt)
            a2[mt] = *reinterpret_cast<const f32x4*>(&bv[2][mt * 16 + lq * 4]);
#pragma unroll
        for (int ks = 0; ks < 2; ++ks)
#pragma unroll
            for (int mt = 0; mt < 4; ++mt)
                a2[mt] = mfma16(ldsA(A2, mt * 2 + ks, lane), b2[ks], a2[mt]);
#pragma unroll
        for (int mt = 0; mt < 4; ++mt)
#pragma unroll
            for (int rr = 0; rr < 4; ++rr)
                a2[mt][rr] = fmaxf(a2[mt][rr], 0.f);

        // ---- stash a2 (channel-pair major): st[cp][e], cp = mt*8+lq*2+{0,1}
#pragma unroll
        for (int mt = 0; mt < 4; ++mt) {
            st[(mt * 8 + lq * 2 + 0) * 16 + l16] = pk2(a2[mt][0], a2[mt][1]);
            st[(mt * 8 + lq * 2 + 1) * 16 + l16] = pk2(a2[mt][2], a2[mt][3]);
        }

        // ---- gate (MFMAs overlap the stash writes)
        bf16x8 b3[2] = { cvt8(a2[0], a2[1]), cvt8(a2[2], a2[3]) };
        f32x4 a3[4];
#pragma unroll
        for (int mt = 0; mt < 4; ++mt)
            a3[mt] = *reinterpret_cast<const f32x4*>(&bv[3][mt * 16 + lq * 4]);
#pragma unroll
        for (int ks = 0; ks < 2; ++ks)
#pragma unroll
            for (int mt = 0; mt < 4; ++mt)
                a3[mt] = mfma16(ldsA(A3, mt * 2 + ks, lane), b3[ks], a3[mt]);
        float gg = 0.f;
#pragma unroll
        for (int mt = 0; mt < 4; ++mt) {
            f32x4 wv = *reinterpret_cast<const f32x4*>(&bv[4][mt * 16 + lq * 4]);
#pragma unroll
            for (int rr = 0; rr < 4; ++rr)
                gg += fmaxf(a3[mt][rr], 0.f) * wv[rr];
        }
        gg += __shfl_xor(gg, 16, 64);
        gg += __shfl_xor(gg, 32, 64);

        float dsel = (lq == 0) ? dx : (lq == 1) ? dy : dz;
        float val  = fminf(fmaxf(dsel * gg, -100.f), 100.f);

        // ---- coord stash rows {x,y},{z,1}: cp = 32, 33
        float vy = __shfl(val, 16 + l16, 64);          // y from lq==1 lane
        if (lq == 0) st[32 * 16 + l16] = pk2(val, vy);
        if (lq == 2) st[33 * 16 + l16] = pk2(val, 1.0f);

        // ---- selection fragment: sel[k][n] = (row(edge k) == row(edge n))
        u16x8 sv;
#pragma unroll
        for (int j = 0; j < 8; ++j) {
            int ks = lq * 8 + j;
            int rk = __shfl(rC, ks & 15, 64);
            sv[j] = (ks < 16 && rk == rC) ? (unsigned short)0x3F80 : (unsigned short)0;
        }
        bf16x8 self = __builtin_bit_cast(bf16x8, sv);

        // ---- per-tile partial sums: 5 MFMAs (4 channel tiles + coord tile)
        f32x4 pg[5];
#pragma unroll
        for (int k = 0; k < 5; ++k) pg[k] = (f32x4){0.f, 0.f, 0.f, 0.f};
        const int elo = (lq & 1) << 3;
#pragma unroll
        for (int tt = 0; tt < 5; ++tt) {
            int cpb = (tt < 4) ? (tt * 8 + (l16 >> 1)) : (32 + ((l16 >> 1) & 1));
            u32x4 wa = *reinterpret_cast<const u32x4*>(st + cpb * 16 + elo);
            u32x4 wb = *reinterpret_cast<const u32x4*>(st + cpb * 16 + elo + 4);
            u16x8 av;
#pragma unroll
            for (int j = 0; j < 4; ++j) {
                av[j]     = (l16 & 1) ? (unsigned short)(wa[j] >> 16)
                                      : (unsigned short)(wa[j] & 0xffffu);
                av[4 + j] = (l16 & 1) ? (unsigned short)(wb[j] >> 16)
                                      : (unsigned short)(wb[j] & 0xffffu);
            }
            pg[tt] = mfma16(__builtin_bit_cast(bf16x8, av), self, pg[tt]);
        }

        // ---- run-leader scatter: first slot of each same-row run in the tile
        int rprev = __shfl(rC, (lane & 48) | ((l16 + 15) & 15), 64);
        if (l16 == 0 || rprev != rC) {
#pragma unroll
            for (int mt = 0; mt < 4; ++mt)
#pragma unroll
                for (int rr = 0; rr < 4; ++rr)
                    atomicAdd(&aggf[(size_t)rC * 64 + mt * 16 + lq * 4 + rr], pg[mt][rr]);
            if (lq == 0) {
#pragma unroll
                for (int rr = 0; rr < 4; ++rr)
                    atomicAdd(&cacc[(size_t)rC * 4 + rr], pg[4][rr]);
            }
        }

        // ---- rotate
        tile = t1; t1 = tile + stride;
        rC = rN; cC = cN; rN = rNN; cN = cNN;
        hr0 = nr0; hr1 = nr1; hc0 = nc0; hc1 = nc1;
        px = npx; py = npy; pz = npz;
    }
}

// ===================== FALLBACK EDGE PASS (atomic, f32) =====================
__global__ __launch_bounds__(512, 4) void egcl_edge_fb(
    const float* __restrict__ h, const float* __restrict__ coord,
    const int* __restrict__ erow, const int* __restrict__ ecol,
    const float* __restrict__ We1, const float* __restrict__ be1,
    const float* __restrict__ We2, const float* __restrict__ be2,
    const float* __restrict__ Wc1, const float* __restrict__ bc1,
    const float* __restrict__ Wc2,
    float* __restrict__ aggf, float* __restrict__ cacc, int E)
{
    __shared__ __align__(16) unsigned short A1[16 * 512];
    __shared__ __align__(16) unsigned short A2[8 * 512];
    __shared__ __align__(16) unsigned short A3[8 * 512];
    __shared__ __align__(16) float bv[5][64];

    const int t = threadIdx.x;
    for (int i = t; i < 8192; i += 512) {
        int j = i & 7, lane = (i >> 3) & 63, fi = i >> 9;
        int mt = fi >> 2, ks = fi & 3;
        int in_ch = ks * 32 + ((lane >> 4) << 3) + j;
        int out   = mt * 16 + (lane & 15);
        A1[i] = f2b(We1[in_ch * 64 + out]);
    }
    for (int i = t; i < 4096; i += 512) {
        int j = i & 7, lane = (i >> 3) & 63, fi = i >> 9;
        int mt = fi >> 1, ks = fi & 1;
        int c   = (ks * 2 + (j >> 2)) * 16 + ((lane >> 4) & 3) * 4 + (j & 3);
        int out = mt * 16 + (lane & 15);
        A2[i] = f2b(We2[c * 64 + out]);
        A3[i] = f2b(Wc1[c * 64 + out]);
    }
    if (t < 64) {
        bv[0][t] = be1[t]; bv[1][t] = We1[128 * 64 + t];
        bv[2][t] = be2[t]; bv[3][t] = bc1[t]; bv[4][t] = Wc2[t];
    }
    __syncthreads();

    const int lane = t & 63;
    const int l16 = lane & 15, lq = lane >> 4;
    const int stride = gridDim.x * 8;
    const int wid = (blockIdx.x << 3) + (t >> 6);
    const int ntile = E >> 4;

    for (int tile = wid; tile < ntile; tile += stride) {
        const int e = (tile << 4) + l16;
        const int r = erow[e], c = ecol[e];
        const float* pr = coord + (size_t)r * 3;
        const float* pc = coord + (size_t)c * 3;
        float dx = pr[0] - pc[0], dy = pr[1] - pc[1], dz = pr[2] - pc[2];
        float rad = dx * dx + dy * dy + dz * dz;
        const f32x4* hr = reinterpret_cast<const f32x4*>(h + (size_t)r * 64);
        const f32x4* hc = reinterpret_cast<const f32x4*>(h + (size_t)c * 64);
        bf16x8 bR[2], bC[2];
#pragma unroll
        for (int ks = 0; ks < 2; ++ks) {
            bR[ks] = cvt8(hr[ks * 8 + lq * 2], hr[ks * 8 + lq * 2 + 1]);
            bC[ks] = cvt8(hc[ks * 8 + lq * 2], hc[ks * 8 + lq * 2 + 1]);
        }
        f32x4 a1[4];
#pragma unroll
        for (int mt = 0; mt < 4; ++mt)
            a1[mt] = *reinterpret_cast<const f32x4*>(&bv[0][mt * 16 + lq * 4]);
#pragma unroll
        for (int ks = 0; ks < 2; ++ks)
#pragma unroll
            for (int mt = 0; mt < 4; ++mt)
                a1[mt] = mfma16(ldsA(A1, mt * 4 + ks, lane), bR[ks], a1[mt]);
#pragma unroll
        for (int ks = 0; ks < 2; ++ks)
#pragma unroll
            for (int mt = 0; mt < 4; ++mt)
                a1[mt] = mfma16(ldsA(A1, mt * 4 + 2 + ks, lane), bC[ks], a1[mt]);
#pragma unroll
        for (int mt = 0; mt < 4; ++mt) {
            f32x4 wv = *reinterpret_cast<const f32x4*>(&bv[1][mt * 16 + lq * 4]);
#pragma unroll
            for (int rr = 0; rr < 4; ++rr)
                a1[mt][rr] = fmaxf(a1[mt][rr] + rad * wv[rr], 0.f);
        }
        bf16x8 b2[2] = { cvt8(a1[0], a1[1]), cvt8(a1[2], a1[3]) };
        f32x4 a2[4];
#pragma unroll
        for (int mt = 0; mt < 4; ++mt)
            a2[mt] = *reinterpret_cast<const f32x4*>(&bv[2][mt * 16 + lq * 4]);
#pragma unroll
        for (int ks = 0; ks < 2; ++ks)
#pragma unroll
            for (int mt = 0; mt < 4; ++mt)
                a2[mt] = mfma16(ldsA(A2, mt * 2 + ks, lane), b2[ks], a2[mt]);
#pragma unroll
        for (int mt = 0; mt < 4; ++mt)
#pragma unroll
            for (int rr = 0; rr < 4; ++rr) {
                a2[mt][rr] = fmaxf(a2[mt][rr], 0.f);
                atomicAdd(&aggf[(size_t)r * 64 + mt * 16 + lq * 4 + rr], a2[mt][rr]);
            }
        bf16x8 b3[2] = { cvt8(a2[0], a2[1]), cvt8(a2[2], a2[3]) };
        f32x4 a3[4];
#pragma unroll
        for (int mt = 0; mt < 4; ++mt)
            a3[mt] = *reinterpret_cast<const f32x4*>(&bv[3][mt * 16 + lq * 4]);
#pragma unroll
        for (int ks = 0; ks < 2; ++ks)
#pragma unroll
            for (int mt = 0; mt < 4; ++mt)
                a3[mt] = mfma16(ldsA(A3, mt * 2 + ks, lane), b3[ks], a3[mt]);
        float gg = 0.f;
#pragma unroll
        for (int mt = 0; mt < 4; ++mt) {
            f32x4 wv = *reinterpret_cast<const f32x4*>(&bv[4][mt * 16 + lq * 4]);
#pragma unroll
            for (int rr = 0; rr < 4; ++rr)
                gg += fmaxf(a3[mt][rr], 0.f) * wv[rr];
        }
        gg += __shfl_xor(gg, 16, 64);
        gg += __shfl_xor(gg, 32, 64);
        float dsel = (lq == 0) ? dx : (lq == 1) ? dy : dz;
        float val  = (lq == 3) ? 1.0f : fminf(fmaxf(dsel * gg, -100.f), 100.f);
        atomicAdd(&cacc[(size_t)r * 4 + lq], val);
    }
}

// ============================== NODE PASS ==============================
__device__ inline void stage_wblock(unsigned short* dst, const float* src, int t, int nthr) {
    for (int i = t; i < 4096; i += nthr) {
        int k = i >> 6, n = i & 63;
        int pos = (((n >> 4) * 2 + (k >> 5)) * 64 + ((((k >> 3) & 3) << 4) | (n & 15))) * 8 + (k & 7);
        dst[pos] = f2b(src[i]);
    }
}

__device__ inline bf16x8 ldsB(const unsigned short* base, int nt, int ks, int lane) {
    return __builtin_bit_cast(bf16x8,
        *reinterpret_cast<const u16x8*>(base + (((nt * 2 + ks) * 64 + lane) << 3)));
}

__global__ __launch_bounds__(256) void egcl_node_fb(
    const float* __restrict__ h, const float* __restrict__ aggf,
    const float* __restrict__ Wn1, const float* __restrict__ bn1,
    const float* __restrict__ Wn2, const float* __restrict__ bn2,
    float* __restrict__ hout, int N)
{
    __shared__ __align__(16) unsigned short wlds[3][4096];
    __shared__ __align__(16) unsigned short mlds[4][16 * 72];
    __shared__ float bn1l[64], bn2l[64];

    const int t = threadIdx.x;
    stage_wblock(wlds[0], Wn1, t, 256);
    stage_wblock(wlds[1], Wn1 + 64 * 64, t, 256);
    stage_wblock(wlds[2], Wn2, t, 256);
    if (t < 64) { bn1l[t] = bn1[t]; bn2l[t] = bn2[t]; }
    __syncthreads();

    const int wave = t >> 6, lane = t & 63;
    const int l16 = lane & 15, lq = lane >> 4;
    const int ntile = N >> 4;
    unsigned short* ml = mlds[wave];

    for (int tile = blockIdx.x * 4 + wave; tile < ntile; tile += gridDim.x * 4) {
        const int nb = tile << 4;
        bf16x8 fH[2], fA[2];
        const f32x4* ph = reinterpret_cast<const f32x4*>(h + (size_t)(nb + l16) * 64);
        const f32x4* pa = reinterpret_cast<const f32x4*>(aggf + (size_t)(nb + l16) * 64);
#pragma unroll
        for (int ks = 0; ks < 2; ++ks) {
            fH[ks] = cvt8(ph[ks * 8 + lq * 2], ph[ks * 8 + lq * 2 + 1]);
            fA[ks] = cvt8(pa[ks * 8 + lq * 2], pa[ks * 8 + lq * 2 + 1]);
        }
        f32x4 acc[4];
#pragma unroll
        for (int nt = 0; nt < 4; ++nt) { float b = bn1l[nt * 16 + l16]; acc[nt] = (f32x4){b, b, b, b}; }
#pragma unroll
        for (int ks = 0; ks < 2; ++ks)
#pragma unroll
            for (int nt = 0; nt < 4; ++nt)
                acc[nt] = mfma16(fH[ks], ldsB(wlds[0], nt, ks, lane), acc[nt]);
#pragma unroll
        for (int ks = 0; ks < 2; ++ks)
#pragma unroll
            for (int nt = 0; nt < 4; ++nt)
                acc[nt] = mfma16(fA[ks], ldsB(wlds[1], nt, ks, lane), acc[nt]);
#pragma unroll
        for (int nt = 0; nt < 4; ++nt)
#pragma unroll
            for (int r = 0; r < 4; ++r)
                ml[(lq * 4 + r) * 72 + nt * 16 + l16] = f2b(fmaxf(acc[nt][r], 0.f));
        bf16x8 fM[2];
#pragma unroll
        for (int ks = 0; ks < 2; ++ks)
            fM[ks] = __builtin_bit_cast(bf16x8,
                *reinterpret_cast<const u16x8*>(ml + l16 * 72 + ks * 32 + lq * 8));
        f32x4 acc2[4];
#pragma unroll
        for (int nt = 0; nt < 4; ++nt) { float b = bn2l[nt * 16 + l16]; acc2[nt] = (f32x4){b, b, b, b}; }
#pragma unroll
        for (int ks = 0; ks < 2; ++ks)
#pragma unroll
            for (int nt = 0; nt < 4; ++nt)
                acc2[nt] = mfma16(fM[ks], ldsB(wlds[2], nt, ks, lane), acc2[nt]);
#pragma unroll
        for (int nt = 0; nt < 4; ++nt)
#pragma unroll
            for (int r = 0; r < 4; ++r) {
                size_t idx = (size_t)(nb + lq * 4 + r) * 64 + nt * 16 + l16;
                hout[idx] = h[idx] + acc2[nt][r];
            }
    }
}

// ---------------------------------------------------------------- helpers
__global__ void f32_to_bf16(const float* __restrict__ src, unsigned short* __restrict__ dst, int n8)
{
    int i = blockIdx.x * 256 + threadIdx.x;
    if (i < n8) {
        const f32x4* p = reinterpret_cast<const f32x4*>(src + (size_t)i * 8);
        bf16x8 v = cvt8(p[0], p[1]);
        reinterpret_cast<u16x8*>(dst)[i] = __builtin_bit_cast(u16x8, v);
    }
}

__global__ void egcl_coord(const float* __restrict__ cacc, float* __restrict__ cout, int N)
{
    int n = blockIdx.x * 256 + threadIdx.x;
    if (n < N) {
        f32x4 c = *reinterpret_cast<const f32x4*>(cacc + (size_t)n * 4);
        float inv = 1.f / fmaxf(c[3], 1.f);
        cout[n * 3 + 0] = c[0] * inv;
        cout[n * 3 + 1] = c[1] * inv;
        cout[n * 3 + 2] = c[2] * inv;
    }
}

extern "C" void kernel_launch(void* const* d_in, const int* in_sizes, int n_in,
                              void* d_out, int out_size, void* d_ws, size_t ws_size,
                              hipStream_t stream)
{
    const float* h     = (const float*)d_in[0];
    const float* coord = (const float*)d_in[1];
    const int*   eidx  = (const int*)d_in[2];
    const float* We1 = (const float*)d_in[3];  const float* be1 = (const float*)d_in[4];
    const float* We2 = (const float*)d_in[5];  const float* be2 = (const float*)d_in[6];
    const float* Wn1 = (const float*)d_in[7];  const float* bn1 = (const float*)d_in[8];
    const float* Wn2 = (const float*)d_in[9];  const float* bn2 = (const float*)d_in[10];
    const float* Wc1 = (const float*)d_in[11]; const float* bc1 = (const float*)d_in[12];
    const float* Wc2 = (const float*)d_in[13];

    const int N = in_sizes[0] / 64;
    const int E = in_sizes[2] / 2;

    float* hout = (float*)d_out;
    float* cout = hout + (size_t)N * 64;

    const int ntileN = N >> 4;
    const int nblkN  = (ntileN + 3) / 4;

    // workspace layout (region [0,1MB) reused: CSR temporaries, then cacc)
    int*      cnt   = (int*)d_ws;                               // N ints
    int*      off   = (int*)((char*)d_ws + (256u << 10));       // N+1 ints
    int*      woff  = (int*)((char*)d_ws + (512u << 10));       // N ints
    int*      bsum  = (int*)((char*)d_ws + (768u << 10));       // 128 ints
    float*    cacc  = (float*)d_ws;                             // N*4 f32 (after CSR)
    unsigned* spack = (unsigned*)((char*)d_ws + (1u << 20));    // E u32
    unsigned short* hb = (unsigned short*)((char*)d_ws + (5u << 20)); // N*64 bf16

    const size_t need_sorted = (5u << 20) + (size_t)N * 128;
    const bool use_sorted = (ws_size >= need_sorted) && N > 0 && (N % 16 == 0)
                            && (N <= 65536) && (E % 16 == 0)
                            && ((size_t)E * 4 <= (4u << 20));

    float* aggf = hout;   // agg scratch aliases h-output region (node pass RAW-safe)

    if (use_sorted) {
        hipMemsetAsync(cnt, 0, (size_t)N * sizeof(int), stream);
        int n8 = N * 8;
        f32_to_bf16<<<(n8 + 255) / 256, 256, 0, stream>>>(h, hb, n8);
        k_hist<<<(E + 255) / 256, 256, 0, stream>>>(eidx, cnt, E);
        k_scan1<<<128, 256, 0, stream>>>(cnt, bsum, N);
        k_scan2<<<1, 128, 0, stream>>>(bsum);
        k_scan3<<<128, 256, 0, stream>>>(cnt, bsum, off, woff, N, E);
        k_scatter<<<(E + 255) / 256, 256, 0, stream>>>(eidx, eidx + E, woff, spack, E);
        // CSR temporaries dead from here; reuse region for cacc
        hipMemsetAsync(cacc, 0, (size_t)N * 4 * sizeof(float), stream);
        hipMemsetAsync(aggf, 0, (size_t)N * 64 * sizeof(float), stream);
        egcl_edge_srt<<<2048, 512, 0, stream>>>(hb, coord, spack,
                                                We1, be1, We2, be2, Wc1, bc1, Wc2,
                                                aggf, cacc, E);
        egcl_node_fb<<<nblkN, 256, 0, stream>>>(h, aggf, Wn1, bn1, Wn2, bn2, hout, N);
        egcl_coord<<<(N + 255) / 256, 256, 0, stream>>>(cacc, cout, N);
    } else {
        hipMemsetAsync(cacc, 0, (size_t)N * 4 * sizeof(float), stream);
        hipMemsetAsync(aggf, 0, (size_t)N * 64 * sizeof(float), stream);
        egcl_edge_fb<<<2048, 512, 0, stream>>>(h, coord, eidx, eidx + E,
                                               We1, be1, We2, be2, Wc1, bc1, Wc2,
                                               aggf, cacc, E);
        egcl_node_fb<<<nblkN, 256, 0, stream>>>(h, aggf, Wn1, bn1, Wn2, bn2, hout, N);
        egcl_coord<<<(N + 255) / 256, 256, 0, stream>>>(cacc, cout, N);
    }
}

// Round 4
// 354.572 us; speedup vs baseline: 2.2543x; 1.0864x over previous
//
#include <hip/hip_runtime.h>

typedef float  f32x4  __attribute__((ext_vector_type(4)));
typedef __bf16 bf16x8 __attribute__((ext_vector_type(8)));
typedef unsigned short u16x8 __attribute__((ext_vector_type(8)));
typedef unsigned int   u32x4 __attribute__((ext_vector_type(4)));

__device__ inline unsigned short f2b(float f) {
    unsigned u = __builtin_bit_cast(unsigned, f);
    u += 0x7fffu + ((u >> 16) & 1u);       // round-to-nearest-even
    return (unsigned short)(u >> 16);
}

__device__ inline unsigned pk2(float a, float b) {
    return (unsigned)f2b(a) | ((unsigned)f2b(b) << 16);
}

__device__ inline f32x4 mfma16(bf16x8 a, bf16x8 b, f32x4 c) {
    return __builtin_amdgcn_mfma_f32_16x16x32_bf16(a, b, c, 0, 0, 0);
}

__device__ inline bf16x8 cvt8(f32x4 a, f32x4 b) {
    u16x8 v;
    v[0] = f2b(a[0]); v[1] = f2b(a[1]); v[2] = f2b(a[2]); v[3] = f2b(a[3]);
    v[4] = f2b(b[0]); v[5] = f2b(b[1]); v[6] = f2b(b[2]); v[7] = f2b(b[3]);
    return __builtin_bit_cast(bf16x8, v);
}

__device__ inline bf16x8 ldsA(const unsigned short* base, int frag, int lane) {
    return __builtin_bit_cast(bf16x8,
        *reinterpret_cast<const u16x8*>(base + ((frag * 64 + lane) << 3)));
}

// ============================ CSR build ============================
__global__ void k_hist(const int* __restrict__ erow, int* __restrict__ cnt, int E)
{
    int i = blockIdx.x * 256 + threadIdx.x;
    if (i < E) atomicAdd(&cnt[erow[i]], 1);
}

// phase 1: per-block partial sums of cnt
__global__ void k_scan1(const int* __restrict__ cnt, int* __restrict__ bsum, int N)
{
    const int b = blockIdx.x, t = threadIdx.x;
    const int chunk = (N + gridDim.x - 1) / gridDim.x;
    const int lo = b * chunk;
    const int hi = min(lo + chunk, N);
    int s = 0;
    for (int i = lo + t; i < hi; i += 256) s += cnt[i];
#pragma unroll
    for (int d = 1; d < 64; d <<= 1) s += __shfl_xor(s, d, 64);
    __shared__ int ws[4];
    if ((t & 63) == 0) ws[t >> 6] = s;
    __syncthreads();
    if (t == 0) bsum[b] = ws[0] + ws[1] + ws[2] + ws[3];
}

// phase 2: exclusive scan of the 128 block sums (one block, 128 threads)
__global__ void k_scan2(int* __restrict__ bsum)
{
    __shared__ int wt[2];
    const int t = threadIdx.x;
    const int lane = t & 63;
    int v = bsum[t];
    int sc = v;
#pragma unroll
    for (int d = 1; d < 64; d <<= 1) { int u = __shfl_up(sc, d, 64); if (lane >= d) sc += u; }
    if (lane == 63) wt[t >> 6] = sc;
    __syncthreads();
    int add = (t >= 64) ? wt[0] : 0;
    bsum[t] = sc - v + add;
}

// phase 3: write per-element exclusive offsets
__global__ void k_scan3(const int* __restrict__ cnt, const int* __restrict__ bsum,
                        int* __restrict__ off, int* __restrict__ woff, int N, int E)
{
    const int b = blockIdx.x, t = threadIdx.x;
    const int chunk = (N + gridDim.x - 1) / gridDim.x;
    const int lo = b * chunk;
    const int hi = min(lo + chunk, N);
    const int tchunk = (chunk + 255) / 256;
    const int tlo = lo + t * tchunk;
    const int thi = min(tlo + tchunk, hi);
    int s = 0;
    for (int i = tlo; i < thi; ++i) s += cnt[i];
    const int lane = t & 63, wv = t >> 6;
    int sc = s;
#pragma unroll
    for (int d = 1; d < 64; d <<= 1) { int u = __shfl_up(sc, d, 64); if (lane >= d) sc += u; }
    __shared__ int ws[4];
    if (lane == 63) ws[wv] = sc;
    __syncthreads();
    int wadd = 0;
#pragma unroll
    for (int k = 0; k < 4; ++k) wadd += (k < wv) ? ws[k] : 0;
    int run = bsum[b] + wadd + (sc - s);
    for (int i = tlo; i < thi; ++i) { off[i] = run; woff[i] = run; run += cnt[i]; }
    if (b == 0 && t == 0) off[N] = E;
}

// scatter edges into row-sorted order; pack (row,col) into one u32 (N <= 65536)
__global__ void k_scatter(const int* __restrict__ erow, const int* __restrict__ ecol,
                          int* __restrict__ woff, unsigned* __restrict__ spack, int E)
{
    int i = blockIdx.x * 256 + threadIdx.x;
    if (i < E) {
        int r = erow[i];
        int pos = atomicAdd(&woff[r], 1);
        spack[pos] = (unsigned)r | ((unsigned)ecol[i] << 16);
    }
}

// ========== SORTED EDGE PASS: R0 pipeline + sel-MFMA partials + packed-row
// leader atomics. Edges in row-sorted order with the double-prefetch tile
// pipeline. Per 16-edge tile, the sel-matrix MFMA reduces to per-node partial
// sums in registers; partials route through the per-wave stash (reused, with
// cp&12 XOR swizzle) and each run-leader issues ONE 64-lane full-row f32
// atomic (256B = 4 dense lines) -> ~2.3 atomic instrs/tile vs 9 in round 0.
__global__ __launch_bounds__(512, 2) void egcl_edge_srt(
    const unsigned short* __restrict__ hb,
    const float* __restrict__ coord,
    const unsigned* __restrict__ spack,
    const float* __restrict__ We1, const float* __restrict__ be1,
    const float* __restrict__ We2, const float* __restrict__ be2,
    const float* __restrict__ Wc1, const float* __restrict__ bc1,
    const float* __restrict__ Wc2,
    float* __restrict__ aggf, float* __restrict__ cacc, int E)
{
    __shared__ __align__(16) unsigned short A1[16 * 512];
    __shared__ __align__(16) unsigned short A2[8 * 512];
    __shared__ __align__(16) unsigned short A3[8 * 512];
    __shared__ __align__(16) float bv[5][64];
    __shared__ __align__(16) unsigned stl[8][34 * 16];   // per-wave stash [cp][slot^swz]

    const int t = threadIdx.x;
    for (int i = t; i < 8192; i += 512) {
        int j = i & 7, lane = (i >> 3) & 63, fi = i >> 9;
        int mt = fi >> 2, ks = fi & 3;
        int in_ch = ks * 32 + ((lane >> 4) << 3) + j;
        int out   = mt * 16 + (lane & 15);
        A1[i] = f2b(We1[in_ch * 64 + out]);
    }
    for (int i = t; i < 4096; i += 512) {
        int j = i & 7, lane = (i >> 3) & 63, fi = i >> 9;
        int mt = fi >> 1, ks = fi & 1;
        int c   = (ks * 2 + (j >> 2)) * 16 + ((lane >> 4) & 3) * 4 + (j & 3);
        int out = mt * 16 + (lane & 15);
        A2[i] = f2b(We2[c * 64 + out]);
        A3[i] = f2b(Wc1[c * 64 + out]);
    }
    if (t < 64) {
        bv[0][t] = be1[t]; bv[1][t] = We1[128 * 64 + t];
        bv[2][t] = be2[t]; bv[3][t] = bc1[t]; bv[4][t] = Wc2[t];
    }
    __syncthreads();

    const int lane = t & 63;
    const int l16 = lane & 15, lq = lane >> 4;
    const int stride = gridDim.x * 8;
    const int wid = (blockIdx.x << 3) + (t >> 6);
    const int ntile = E >> 4;
    const int last = ntile - 1;
    unsigned* st = stl[t >> 6];

    int tile = wid;
    if (tile >= ntile) return;

    // ---------------- prologue: tile 0 data + tile 1 indices
    int eC = (tile << 4) + l16;
    unsigned pC = spack[eC];
    int rC = (int)(pC & 0xffffu), cC = (int)(pC >> 16);
    u16x8 hr0, hr1, hc0, hc1;
    {
        const u16x8* hr = reinterpret_cast<const u16x8*>(hb + (size_t)rC * 64);
        const u16x8* hc = reinterpret_cast<const u16x8*>(hb + (size_t)cC * 64);
        hr0 = hr[lq]; hr1 = hr[4 + lq]; hc0 = hc[lq]; hc1 = hc[4 + lq];
    }
    float px = 0.f, py = 0.f, pz = 0.f;
    if (lq < 2) {
        int node = (lq == 0) ? rC : cC;
        const float* pp = coord + (size_t)node * 3;
        px = pp[0]; py = pp[1]; pz = pp[2];
    }
    int t1 = tile + stride;
    int tn = (t1 < ntile) ? t1 : last;
    unsigned pN = spack[(tn << 4) + l16];
    int rN = (int)(pN & 0xffffu), cN = (int)(pN >> 16);

    for (; tile < ntile; ) {
        // ---- stage 1: issue next tile's h/coord loads
        u16x8 nr0, nr1, nc0, nc1;
        {
            const u16x8* hr = reinterpret_cast<const u16x8*>(hb + (size_t)rN * 64);
            const u16x8* hc = reinterpret_cast<const u16x8*>(hb + (size_t)cN * 64);
            nr0 = hr[lq]; nr1 = hr[4 + lq]; nc0 = hc[lq]; nc1 = hc[4 + lq];
        }
        float npx = 0.f, npy = 0.f, npz = 0.f;
        if (lq < 2) {
            int node = (lq == 0) ? rN : cN;
            const float* pp = coord + (size_t)node * 3;
            npx = pp[0]; npy = pp[1]; npz = pp[2];
        }
        // ---- stage 2: issue tile+2 index loads
        int t2 = tile + 2 * stride;
        int t2c = (t2 < ntile) ? t2 : last;
        unsigned pNN = spack[(t2c << 4) + l16];
        int rNN = (int)(pNN & 0xffffu), cNN = (int)(pNN >> 16);

        // ---- stage 3: compute current tile
        float prx = __shfl(px, l16, 64), pry = __shfl(py, l16, 64), prz = __shfl(pz, l16, 64);
        float pcx = __shfl(px, 16 + l16, 64), pcy = __shfl(py, 16 + l16, 64), pcz = __shfl(pz, 16 + l16, 64);
        float dx = prx - pcx, dy = pry - pcy, dz = prz - pcz;
        float rad = dx * dx + dy * dy + dz * dz;

        bf16x8 bR[2] = { __builtin_bit_cast(bf16x8, hr0), __builtin_bit_cast(bf16x8, hr1) };
        bf16x8 bC[2] = { __builtin_bit_cast(bf16x8, hc0), __builtin_bit_cast(bf16x8, hc1) };

        // layer 1
        f32x4 a1[4];
#pragma unroll
        for (int mt = 0; mt < 4; ++mt)
            a1[mt] = *reinterpret_cast<const f32x4*>(&bv[0][mt * 16 + lq * 4]);
#pragma unroll
        for (int ks = 0; ks < 2; ++ks)
#pragma unroll
            for (int mt = 0; mt < 4; ++mt)
                a1[mt] = mfma16(ldsA(A1, mt * 4 + ks, lane), bR[ks], a1[mt]);
#pragma unroll
        for (int ks = 0; ks < 2; ++ks)
#pragma unroll
            for (int mt = 0; mt < 4; ++mt)
                a1[mt] = mfma16(ldsA(A1, mt * 4 + 2 + ks, lane), bC[ks], a1[mt]);
#pragma unroll
        for (int mt = 0; mt < 4; ++mt) {
            f32x4 wv = *reinterpret_cast<const f32x4*>(&bv[1][mt * 16 + lq * 4]);
#pragma unroll
            for (int rr = 0; rr < 4; ++rr)
                a1[mt][rr] = fmaxf(a1[mt][rr] + rad * wv[rr], 0.f);
        }

        // layer 2
        bf16x8 b2[2] = { cvt8(a1[0], a1[1]), cvt8(a1[2], a1[3]) };
        f32x4 a2[4];
#pragma unroll
        for (int mt = 0; mt < 4; ++mt)
            a2[mt] = *reinterpret_cast<const f32x4*>(&bv[2][mt * 16 + lq * 4]);
#pragma unroll
        for (int ks = 0; ks < 2; ++ks)
#pragma unroll
            for (int mt = 0; mt < 4; ++mt)
                a2[mt] = mfma16(ldsA(A2, mt * 2 + ks, lane), b2[ks], a2[mt]);
#pragma unroll
        for (int mt = 0; mt < 4; ++mt)
#pragma unroll
            for (int rr = 0; rr < 4; ++rr)
                a2[mt][rr] = fmaxf(a2[mt][rr], 0.f);

        // ---- stash a2 (channel-pair major, swizzled): st[cp][l16 ^ (cp&12)]
#pragma unroll
        for (int mt = 0; mt < 4; ++mt) {
            int cp0 = mt * 8 + lq * 2;
            int sw  = l16 ^ (cp0 & 12);
            st[(cp0 + 0) * 16 + sw] = pk2(a2[mt][0], a2[mt][1]);
            st[(cp0 + 1) * 16 + sw] = pk2(a2[mt][2], a2[mt][3]);
        }

        // ---- gate (MFMAs overlap the stash writes)
        bf16x8 b3[2] = { cvt8(a2[0], a2[1]), cvt8(a2[2], a2[3]) };
        f32x4 a3[4];
#pragma unroll
        for (int mt = 0; mt < 4; ++mt)
            a3[mt] = *reinterpret_cast<const f32x4*>(&bv[3][mt * 16 + lq * 4]);
#pragma unroll
        for (int ks = 0; ks < 2; ++ks)
#pragma unroll
            for (int mt = 0; mt < 4; ++mt)
                a3[mt] = mfma16(ldsA(A3, mt * 2 + ks, lane), b3[ks], a3[mt]);
        float gg = 0.f;
#pragma unroll
        for (int mt = 0; mt < 4; ++mt) {
            f32x4 wv = *reinterpret_cast<const f32x4*>(&bv[4][mt * 16 + lq * 4]);
#pragma unroll
            for (int rr = 0; rr < 4; ++rr)
                gg += fmaxf(a3[mt][rr], 0.f) * wv[rr];
        }
        gg += __shfl_xor(gg, 16, 64);
        gg += __shfl_xor(gg, 32, 64);

        float dsel = (lq == 0) ? dx : (lq == 1) ? dy : dz;
        float val  = fminf(fmaxf(dsel * gg, -100.f), 100.f);

        // ---- coord stash rows {x,y},{z,1}: cp = 32, 33 (swizzle = 0 there)
        float vy = __shfl(val, 16 + l16, 64);          // y from lq==1 lane
        if (lq == 0) st[32 * 16 + l16] = pk2(val, vy);
        if (lq == 2) st[33 * 16 + l16] = pk2(val, 1.0f);

        // ---- selection fragment: sel[k][n] = (row(edge k) == row(edge n))
        u16x8 sv;
#pragma unroll
        for (int j = 0; j < 8; ++j) {
            int ks = lq * 8 + j;
            int rk = __shfl(rC, ks & 15, 64);
            sv[j] = (ks < 16 && rk == rC) ? (unsigned short)0x3F80 : (unsigned short)0;
        }
        bf16x8 self = __builtin_bit_cast(bf16x8, sv);

        // ---- per-tile partial sums: 5 MFMAs (4 channel tiles + coord tile)
        f32x4 pg[5];
#pragma unroll
        for (int k = 0; k < 5; ++k) pg[k] = (f32x4){0.f, 0.f, 0.f, 0.f};
        const int elo = (lq & 1) << 3;
#pragma unroll
        for (int tt = 0; tt < 5; ++tt) {
            int cpb = (tt < 4) ? (tt * 8 + (l16 >> 1)) : (32 + ((l16 >> 1) & 1));
            int c   = cpb & 12;
            u32x4 wa = *reinterpret_cast<const u32x4*>(st + cpb * 16 + (elo ^ c));
            u32x4 wb = *reinterpret_cast<const u32x4*>(st + cpb * 16 + ((elo + 4) ^ c));
            u16x8 av;
#pragma unroll
            for (int j = 0; j < 4; ++j) {
                av[j]     = (l16 & 1) ? (unsigned short)(wa[j] >> 16)
                                      : (unsigned short)(wa[j] & 0xffffu);
                av[4 + j] = (l16 & 1) ? (unsigned short)(wb[j] >> 16)
                                      : (unsigned short)(wb[j] & 0xffffu);
            }
            pg[tt] = mfma16(__builtin_bit_cast(bf16x8, av), self, pg[tt]);
        }

        // ---- write partials back to the stash (feat stash fully consumed)
#pragma unroll
        for (int mt = 0; mt < 4; ++mt) {
            int cp0 = mt * 8 + lq * 2;
            int sw  = l16 ^ (cp0 & 12);
            st[(cp0 + 0) * 16 + sw] = pk2(pg[mt][0], pg[mt][1]);
            st[(cp0 + 1) * 16 + sw] = pk2(pg[mt][2], pg[mt][3]);
        }

        // ---- leader detection (run starts within the tile)
        int rprev = __shfl(rC, (lane & 48) | ((l16 + 15) & 15), 64);
        bool lead = (l16 == 0) || (rprev != rC);

        // coord partial scatter: 4 f32 atomics per leader (from its lq==0 lane)
        if (lead && lq == 0) {
#pragma unroll
            for (int rr = 0; rr < 4; ++rr)
                atomicAdd(&cacc[(size_t)rC * 4 + rr], pg[4][rr]);
        }

        // agg partial scatter: ONE full-row 64-lane f32 atomic per leader
        unsigned m = (unsigned)(__ballot(lead) & 0xFFFFull);
        const int cpr = lane >> 1;
        while (m) {
            int s = __builtin_ctz(m); m &= m - 1;
            int rw = __shfl(rC, s, 64);
            unsigned pkd = st[cpr * 16 + (s ^ (cpr & 12))];
            float v = __builtin_bit_cast(float,
                      (lane & 1) ? (pkd & 0xffff0000u) : (pkd << 16));
            atomicAdd(&aggf[(size_t)rw * 64 + lane], v);
        }

        // ---- rotate
        tile = t1; t1 = tile + stride;
        rC = rN; cC = cN; rN = rNN; cN = cNN;
        hr0 = nr0; hr1 = nr1; hc0 = nc0; hc1 = nc1;
        px = npx; py = npy; pz = npz;
    }
}

// ===================== FALLBACK EDGE PASS (atomic, f32) =====================
__global__ __launch_bounds__(512, 4) void egcl_edge_fb(
    const float* __restrict__ h, const float* __restrict__ coord,
    const int* __restrict__ erow, const int* __restrict__ ecol,
    const float* __restrict__ We1, const float* __restrict__ be1,
    const float* __restrict__ We2, const float* __restrict__ be2,
    const float* __restrict__ Wc1, const float* __restrict__ bc1,
    const float* __restrict__ Wc2,
    float* __restrict__ aggf, float* __restrict__ cacc, int E)
{
    __shared__ __align__(16) unsigned short A1[16 * 512];
    __shared__ __align__(16) unsigned short A2[8 * 512];
    __shared__ __align__(16) unsigned short A3[8 * 512];
    __shared__ __align__(16) float bv[5][64];

    const int t = threadIdx.x;
    for (int i = t; i < 8192; i += 512) {
        int j = i & 7, lane = (i >> 3) & 63, fi = i >> 9;
        int mt = fi >> 2, ks = fi & 3;
        int in_ch = ks * 32 + ((lane >> 4) << 3) + j;
        int out   = mt * 16 + (lane & 15);
        A1[i] = f2b(We1[in_ch * 64 + out]);
    }
    for (int i = t; i < 4096; i += 512) {
        int j = i & 7, lane = (i >> 3) & 63, fi = i >> 9;
        int mt = fi >> 1, ks = fi & 1;
        int c   = (ks * 2 + (j >> 2)) * 16 + ((lane >> 4) & 3) * 4 + (j & 3);
        int out = mt * 16 + (lane & 15);
        A2[i] = f2b(We2[c * 64 + out]);
        A3[i] = f2b(Wc1[c * 64 + out]);
    }
    if (t < 64) {
        bv[0][t] = be1[t]; bv[1][t] = We1[128 * 64 + t];
        bv[2][t] = be2[t]; bv[3][t] = bc1[t]; bv[4][t] = Wc2[t];
    }
    __syncthreads();

    const int lane = t & 63;
    const int l16 = lane & 15, lq = lane >> 4;
    const int stride = gridDim.x * 8;
    const int wid = (blockIdx.x << 3) + (t >> 6);
    const int ntile = E >> 4;

    for (int tile = wid; tile < ntile; tile += stride) {
        const int e = (tile << 4) + l16;
        const int r = erow[e], c = ecol[e];
        const float* pr = coord + (size_t)r * 3;
        const float* pc = coord + (size_t)c * 3;
        float dx = pr[0] - pc[0], dy = pr[1] - pc[1], dz = pr[2] - pc[2];
        float rad = dx * dx + dy * dy + dz * dz;
        const f32x4* hr = reinterpret_cast<const f32x4*>(h + (size_t)r * 64);
        const f32x4* hc = reinterpret_cast<const f32x4*>(h + (size_t)c * 64);
        bf16x8 bR[2], bC[2];
#pragma unroll
        for (int ks = 0; ks < 2; ++ks) {
            bR[ks] = cvt8(hr[ks * 8 + lq * 2], hr[ks * 8 + lq * 2 + 1]);
            bC[ks] = cvt8(hc[ks * 8 + lq * 2], hc[ks * 8 + lq * 2 + 1]);
        }
        f32x4 a1[4];
#pragma unroll
        for (int mt = 0; mt < 4; ++mt)
            a1[mt] = *reinterpret_cast<const f32x4*>(&bv[0][mt * 16 + lq * 4]);
#pragma unroll
        for (int ks = 0; ks < 2; ++ks)
#pragma unroll
            for (int mt = 0; mt < 4; ++mt)
                a1[mt] = mfma16(ldsA(A1, mt * 4 + ks, lane), bR[ks], a1[mt]);
#pragma unroll
        for (int ks = 0; ks < 2; ++ks)
#pragma unroll
            for (int mt = 0; mt < 4; ++mt)
                a1[mt] = mfma16(ldsA(A1, mt * 4 + 2 + ks, lane), bC[ks], a1[mt]);
#pragma unroll
        for (int mt = 0; mt < 4; ++mt) {
            f32x4 wv = *reinterpret_cast<const f32x4*>(&bv[1][mt * 16 + lq * 4]);
#pragma unroll
            for (int rr = 0; rr < 4; ++rr)
                a1[mt][rr] = fmaxf(a1[mt][rr] + rad * wv[rr], 0.f);
        }
        bf16x8 b2[2] = { cvt8(a1[0], a1[1]), cvt8(a1[2], a1[3]) };
        f32x4 a2[4];
#pragma unroll
        for (int mt = 0; mt < 4; ++mt)
            a2[mt] = *reinterpret_cast<const f32x4*>(&bv[2][mt * 16 + lq * 4]);
#pragma unroll
        for (int ks = 0; ks < 2; ++ks)
#pragma unroll
            for (int mt = 0; mt < 4; ++mt)
                a2[mt] = mfma16(ldsA(A2, mt * 2 + ks, lane), b2[ks], a2[mt]);
#pragma unroll
        for (int mt = 0; mt < 4; ++mt)
#pragma unroll
            for (int rr = 0; rr < 4; ++rr) {
                a2[mt][rr] = fmaxf(a2[mt][rr], 0.f);
                atomicAdd(&aggf[(size_t)r * 64 + mt * 16 + lq * 4 + rr], a2[mt][rr]);
            }
        bf16x8 b3[2] = { cvt8(a2[0], a2[1]), cvt8(a2[2], a2[3]) };
        f32x4 a3[4];
#pragma unroll
        for (int mt = 0; mt < 4; ++mt)
            a3[mt] = *reinterpret_cast<const f32x4*>(&bv[3][mt * 16 + lq * 4]);
#pragma unroll
        for (int ks = 0; ks < 2; ++ks)
#pragma unroll
            for (int mt = 0; mt < 4; ++mt)
                a3[mt] = mfma16(ldsA(A3, mt * 2 + ks, lane), b3[ks], a3[mt]);
        float gg = 0.f;
#pragma unroll
        for (int mt = 0; mt < 4; ++mt) {
            f32x4 wv = *reinterpret_cast<const f32x4*>(&bv[4][mt * 16 + lq * 4]);
#pragma unroll
            for (int rr = 0; rr < 4; ++rr)
                gg += fmaxf(a3[mt][rr], 0.f) * wv[rr];
        }
        gg += __shfl_xor(gg, 16, 64);
        gg += __shfl_xor(gg, 32, 64);
        float dsel = (lq == 0) ? dx : (lq == 1) ? dy : dz;
        float val  = (lq == 3) ? 1.0f : fminf(fmaxf(dsel * gg, -100.f), 100.f);
        atomicAdd(&cacc[(size_t)r * 4 + lq], val);
    }
}

// ============================== NODE PASS ==============================
__device__ inline void stage_wblock(unsigned short* dst, const float* src, int t, int nthr) {
    for (int i = t; i < 4096; i += nthr) {
        int k = i >> 6, n = i & 63;
        int pos = (((n >> 4) * 2 + (k >> 5)) * 64 + ((((k >> 3) & 3) << 4) | (n & 15))) * 8 + (k & 7);
        dst[pos] = f2b(src[i]);
    }
}

__device__ inline bf16x8 ldsB(const unsigned short* base, int nt, int ks, int lane) {
    return __builtin_bit_cast(bf16x8,
        *reinterpret_cast<const u16x8*>(base + (((nt * 2 + ks) * 64 + lane) << 3)));
}

__global__ __launch_bounds__(256) void egcl_node_fb(
    const float* __restrict__ h, const float* __restrict__ aggf,
    const float* __restrict__ Wn1, const float* __restrict__ bn1,
    const float* __restrict__ Wn2, const float* __restrict__ bn2,
    float* __restrict__ hout, int N)
{
    __shared__ __align__(16) unsigned short wlds[3][4096];
    __shared__ __align__(16) unsigned short mlds[4][16 * 72];
    __shared__ float bn1l[64], bn2l[64];

    const int t = threadIdx.x;
    stage_wblock(wlds[0], Wn1, t, 256);
    stage_wblock(wlds[1], Wn1 + 64 * 64, t, 256);
    stage_wblock(wlds[2], Wn2, t, 256);
    if (t < 64) { bn1l[t] = bn1[t]; bn2l[t] = bn2[t]; }
    __syncthreads();

    const int wave = t >> 6, lane = t & 63;
    const int l16 = lane & 15, lq = lane >> 4;
    const int ntile = N >> 4;
    unsigned short* ml = mlds[wave];

    for (int tile = blockIdx.x * 4 + wave; tile < ntile; tile += gridDim.x * 4) {
        const int nb = tile << 4;
        bf16x8 fH[2], fA[2];
        const f32x4* ph = reinterpret_cast<const f32x4*>(h + (size_t)(nb + l16) * 64);
        const f32x4* pa = reinterpret_cast<const f32x4*>(aggf + (size_t)(nb + l16) * 64);
#pragma unroll
        for (int ks = 0; ks < 2; ++ks) {
            fH[ks] = cvt8(ph[ks * 8 + lq * 2], ph[ks * 8 + lq * 2 + 1]);
            fA[ks] = cvt8(pa[ks * 8 + lq * 2], pa[ks * 8 + lq * 2 + 1]);
        }
        f32x4 acc[4];
#pragma unroll
        for (int nt = 0; nt < 4; ++nt) { float b = bn1l[nt * 16 + l16]; acc[nt] = (f32x4){b, b, b, b}; }
#pragma unroll
        for (int ks = 0; ks < 2; ++ks)
#pragma unroll
            for (int nt = 0; nt < 4; ++nt)
                acc[nt] = mfma16(fH[ks], ldsB(wlds[0], nt, ks, lane), acc[nt]);
#pragma unroll
        for (int ks = 0; ks < 2; ++ks)
#pragma unroll
            for (int nt = 0; nt < 4; ++nt)
                acc[nt] = mfma16(fA[ks], ldsB(wlds[1], nt, ks, lane), acc[nt]);
#pragma unroll
        for (int nt = 0; nt < 4; ++nt)
#pragma unroll
            for (int r = 0; r < 4; ++r)
                ml[(lq * 4 + r) * 72 + nt * 16 + l16] = f2b(fmaxf(acc[nt][r], 0.f));
        bf16x8 fM[2];
#pragma unroll
        for (int ks = 0; ks < 2; ++ks)
            fM[ks] = __builtin_bit_cast(bf16x8,
                *reinterpret_cast<const u16x8*>(ml + l16 * 72 + ks * 32 + lq * 8));
        f32x4 acc2[4];
#pragma unroll
        for (int nt = 0; nt < 4; ++nt) { float b = bn2l[nt * 16 + l16]; acc2[nt] = (f32x4){b, b, b, b}; }
#pragma unroll
        for (int ks = 0; ks < 2; ++ks)
#pragma unroll
            for (int nt = 0; nt < 4; ++nt)
                acc2[nt] = mfma16(fM[ks], ldsB(wlds[2], nt, ks, lane), acc2[nt]);
#pragma unroll
        for (int nt = 0; nt < 4; ++nt)
#pragma unroll
            for (int r = 0; r < 4; ++r) {
                size_t idx = (size_t)(nb + lq * 4 + r) * 64 + nt * 16 + l16;
                hout[idx] = h[idx] + acc2[nt][r];
            }
    }
}

// ---------------------------------------------------------------- helpers
__global__ void f32_to_bf16(const float* __restrict__ src, unsigned short* __restrict__ dst, int n8)
{
    int i = blockIdx.x * 256 + threadIdx.x;
    if (i < n8) {
        const f32x4* p = reinterpret_cast<const f32x4*>(src + (size_t)i * 8);
        bf16x8 v = cvt8(p[0], p[1]);
        reinterpret_cast<u16x8*>(dst)[i] = __builtin_bit_cast(u16x8, v);
    }
}

__global__ void egcl_coord(const float* __restrict__ cacc, float* __restrict__ cout, int N)
{
    int n = blockIdx.x * 256 + threadIdx.x;
    if (n < N) {
        f32x4 c = *reinterpret_cast<const f32x4*>(cacc + (size_t)n * 4);
        float inv = 1.f / fmaxf(c[3], 1.f);
        cout[n * 3 + 0] = c[0] * inv;
        cout[n * 3 + 1] = c[1] * inv;
        cout[n * 3 + 2] = c[2] * inv;
    }
}

extern "C" void kernel_launch(void* const* d_in, const int* in_sizes, int n_in,
                              void* d_out, int out_size, void* d_ws, size_t ws_size,
                              hipStream_t stream)
{
    const float* h     = (const float*)d_in[0];
    const float* coord = (const float*)d_in[1];
    const int*   eidx  = (const int*)d_in[2];
    const float* We1 = (const float*)d_in[3];  const float* be1 = (const float*)d_in[4];
    const float* We2 = (const float*)d_in[5];  const float* be2 = (const float*)d_in[6];
    const float* Wn1 = (const float*)d_in[7];  const float* bn1 = (const float*)d_in[8];
    const float* Wn2 = (const float*)d_in[9];  const float* bn2 = (const float*)d_in[10];
    const float* Wc1 = (const float*)d_in[11]; const float* bc1 = (const float*)d_in[12];
    const float* Wc2 = (const float*)d_in[13];

    const int N = in_sizes[0] / 64;
    const int E = in_sizes[2] / 2;

    float* hout = (float*)d_out;
    float* cout = hout + (size_t)N * 64;

    const int ntileN = N >> 4;
    const int nblkN  = (ntileN + 3) / 4;

    // workspace layout (region [0,1MB) reused: CSR temporaries, then cacc)
    int*      cnt   = (int*)d_ws;                               // N ints
    int*      off   = (int*)((char*)d_ws + (256u << 10));       // N+1 ints
    int*      woff  = (int*)((char*)d_ws + (512u << 10));       // N ints
    int*      bsum  = (int*)((char*)d_ws + (768u << 10));       // 128 ints
    float*    cacc  = (float*)d_ws;                             // N*4 f32 (after CSR)
    unsigned* spack = (unsigned*)((char*)d_ws + (1u << 20));    // E u32
    unsigned short* hb = (unsigned short*)((char*)d_ws + (5u << 20)); // N*64 bf16

    const size_t need_sorted = (5u << 20) + (size_t)N * 128;
    const bool use_sorted = (ws_size >= need_sorted) && N > 0 && (N % 16 == 0)
                            && (N <= 65536) && (E % 16 == 0)
                            && ((size_t)E * 4 <= (4u << 20));

    float* aggf = hout;   // agg scratch aliases h-output region (node pass RAW-safe)

    if (use_sorted) {
        hipMemsetAsync(cnt, 0, (size_t)N * sizeof(int), stream);
        int n8 = N * 8;
        f32_to_bf16<<<(n8 + 255) / 256, 256, 0, stream>>>(h, hb, n8);
        k_hist<<<(E + 255) / 256, 256, 0, stream>>>(eidx, cnt, E);
        k_scan1<<<128, 256, 0, stream>>>(cnt, bsum, N);
        k_scan2<<<1, 128, 0, stream>>>(bsum);
        k_scan3<<<128, 256, 0, stream>>>(cnt, bsum, off, woff, N, E);
        k_scatter<<<(E + 255) / 256, 256, 0, stream>>>(eidx, eidx + E, woff, spack, E);
        // CSR temporaries dead from here; reuse region for cacc
        hipMemsetAsync(cacc, 0, (size_t)N * 4 * sizeof(float), stream);
        hipMemsetAsync(aggf, 0, (size_t)N * 64 * sizeof(float), stream);
        egcl_edge_srt<<<2048, 512, 0, stream>>>(hb, coord, spack,
                                                We1, be1, We2, be2, Wc1, bc1, Wc2,
                                                aggf, cacc, E);
        egcl_node_fb<<<nblkN, 256, 0, stream>>>(h, aggf, Wn1, bn1, Wn2, bn2, hout, N);
        egcl_coord<<<(N + 255) / 256, 256, 0, stream>>>(cacc, cout, N);
    } else {
        hipMemsetAsync(cacc, 0, (size_t)N * 4 * sizeof(float), stream);
        hipMemsetAsync(aggf, 0, (size_t)N * 64 * sizeof(float), stream);
        egcl_edge_fb<<<2048, 512, 0, stream>>>(h, coord, eidx, eidx + E,
                                               We1, be1, We2, be2, Wc1, bc1, Wc2,
                                               aggf, cacc, E);
        egcl_node_fb<<<nblkN, 256, 0, stream>>>(h, aggf, Wn1, bn1, Wn2, bn2, hout, N);
        egcl_coord<<<(N + 255) / 256, 256, 0, stream>>>(cacc, cout, N);
    }
}

// Round 5
// 247.653 us; speedup vs baseline: 3.2275x; 1.4317x over previous
//
#include <hip/hip_runtime.h>

typedef float  f32x4  __attribute__((ext_vector_type(4)));
typedef __bf16 bf16x8 __attribute__((ext_vector_type(8)));
typedef unsigned short u16x8 __attribute__((ext_vector_type(8)));
typedef unsigned int   u32x4 __attribute__((ext_vector_type(4)));

__device__ inline unsigned short f2b(float f) {
    unsigned u = __builtin_bit_cast(unsigned, f);
    u += 0x7fffu + ((u >> 16) & 1u);       // round-to-nearest-even
    return (unsigned short)(u >> 16);
}

__device__ inline unsigned pk2(float a, float b) {
    return (unsigned)f2b(a) | ((unsigned)f2b(b) << 16);
}

__device__ inline f32x4 mfma16(bf16x8 a, bf16x8 b, f32x4 c) {
    return __builtin_amdgcn_mfma_f32_16x16x32_bf16(a, b, c, 0, 0, 0);
}

__device__ inline bf16x8 cvt8(f32x4 a, f32x4 b) {
    u16x8 v;
    v[0] = f2b(a[0]); v[1] = f2b(a[1]); v[2] = f2b(a[2]); v[3] = f2b(a[3]);
    v[4] = f2b(b[0]); v[5] = f2b(b[1]); v[6] = f2b(b[2]); v[7] = f2b(b[3]);
    return __builtin_bit_cast(bf16x8, v);
}

__device__ inline bf16x8 ldsA(const unsigned short* base, int frag, int lane) {
    return __builtin_bit_cast(bf16x8,
        *reinterpret_cast<const u16x8*>(base + ((frag * 64 + lane) << 3)));
}

__device__ inline void atom_pk(unsigned short* p, unsigned d) {
    asm volatile("global_atomic_pk_add_bf16 %0, %1, off" :: "v"(p), "v"(d) : "memory");
}

// ============================ CSR build ============================
__global__ void k_hist(const int* __restrict__ erow, int* __restrict__ cnt, int E)
{
    int i = blockIdx.x * 256 + threadIdx.x;
    if (i < E) atomicAdd(&cnt[erow[i]], 1);
}

// phase 1: per-block partial sums of cnt
__global__ void k_scan1(const int* __restrict__ cnt, int* __restrict__ bsum, int N)
{
    const int b = blockIdx.x, t = threadIdx.x;
    const int chunk = (N + gridDim.x - 1) / gridDim.x;
    const int lo = b * chunk;
    const int hi = min(lo + chunk, N);
    int s = 0;
    for (int i = lo + t; i < hi; i += 256) s += cnt[i];
#pragma unroll
    for (int d = 1; d < 64; d <<= 1) s += __shfl_xor(s, d, 64);
    __shared__ int ws[4];
    if ((t & 63) == 0) ws[t >> 6] = s;
    __syncthreads();
    if (t == 0) bsum[b] = ws[0] + ws[1] + ws[2] + ws[3];
}

// phase 2: exclusive scan of the 128 block sums (one block, 128 threads)
__global__ void k_scan2(int* __restrict__ bsum)
{
    __shared__ int wt[2];
    const int t = threadIdx.x;
    const int lane = t & 63;
    int v = bsum[t];
    int sc = v;
#pragma unroll
    for (int d = 1; d < 64; d <<= 1) { int u = __shfl_up(sc, d, 64); if (lane >= d) sc += u; }
    if (lane == 63) wt[t >> 6] = sc;
    __syncthreads();
    int add = (t >= 64) ? wt[0] : 0;
    bsum[t] = sc - v + add;
}

// phase 3: write per-element exclusive offsets
__global__ void k_scan3(const int* __restrict__ cnt, const int* __restrict__ bsum,
                        int* __restrict__ off, int* __restrict__ woff, int N, int E)
{
    const int b = blockIdx.x, t = threadIdx.x;
    const int chunk = (N + gridDim.x - 1) / gridDim.x;
    const int lo = b * chunk;
    const int hi = min(lo + chunk, N);
    const int tchunk = (chunk + 255) / 256;
    const int tlo = lo + t * tchunk;
    const int thi = min(tlo + tchunk, hi);
    int s = 0;
    for (int i = tlo; i < thi; ++i) s += cnt[i];
    const int lane = t & 63, wv = t >> 6;
    int sc = s;
#pragma unroll
    for (int d = 1; d < 64; d <<= 1) { int u = __shfl_up(sc, d, 64); if (lane >= d) sc += u; }
    __shared__ int ws[4];
    if (lane == 63) ws[wv] = sc;
    __syncthreads();
    int wadd = 0;
#pragma unroll
    for (int k = 0; k < 4; ++k) wadd += (k < wv) ? ws[k] : 0;
    int run = bsum[b] + wadd + (sc - s);
    for (int i = tlo; i < thi; ++i) { off[i] = run; woff[i] = run; run += cnt[i]; }
    if (b == 0 && t == 0) off[N] = E;
}

// scatter edges into row-sorted order; pack (row,col) into one u32 (N <= 65536)
__global__ void k_scatter(const int* __restrict__ erow, const int* __restrict__ ecol,
                          int* __restrict__ woff, unsigned* __restrict__ spack, int E)
{
    int i = blockIdx.x * 256 + threadIdx.x;
    if (i < E) {
        int r = erow[i];
        int pos = atomicAdd(&woff[r], 1);
        spack[pos] = (unsigned)r | ((unsigned)ecol[i] << 16);
    }
}

// ========== SORTED EDGE PASS: R0 pipeline + sel-MFMA partials + pk-bf16
// leader atomics INTO WORKSPACE. d_out atomics/memsets are fine-grained
// (no L2 merging: R3/R4 measured ~30B HBM-write per lane-atomic vs 4.5B for
// ws-destined pk atomics in R0) -- so partials drain via
// global_atomic_pk_add_bf16 into aggb in d_ws, two leaders per 64-lane op.
__global__ __launch_bounds__(512, 2) void egcl_edge_srt(
    const unsigned short* __restrict__ hb,
    const float* __restrict__ coord,
    const unsigned* __restrict__ spack,
    const float* __restrict__ We1, const float* __restrict__ be1,
    const float* __restrict__ We2, const float* __restrict__ be2,
    const float* __restrict__ Wc1, const float* __restrict__ bc1,
    const float* __restrict__ Wc2,
    unsigned short* __restrict__ aggb, float* __restrict__ cacc, int E)
{
    __shared__ __align__(16) unsigned short A1[16 * 512];
    __shared__ __align__(16) unsigned short A2[8 * 512];
    __shared__ __align__(16) unsigned short A3[8 * 512];
    __shared__ __align__(16) float bv[5][64];
    __shared__ __align__(16) unsigned stl[8][34 * 16];   // per-wave stash [cp][slot^swz]

    const int t = threadIdx.x;
    for (int i = t; i < 8192; i += 512) {
        int j = i & 7, lane = (i >> 3) & 63, fi = i >> 9;
        int mt = fi >> 2, ks = fi & 3;
        int in_ch = ks * 32 + ((lane >> 4) << 3) + j;
        int out   = mt * 16 + (lane & 15);
        A1[i] = f2b(We1[in_ch * 64 + out]);
    }
    for (int i = t; i < 4096; i += 512) {
        int j = i & 7, lane = (i >> 3) & 63, fi = i >> 9;
        int mt = fi >> 1, ks = fi & 1;
        int c   = (ks * 2 + (j >> 2)) * 16 + ((lane >> 4) & 3) * 4 + (j & 3);
        int out = mt * 16 + (lane & 15);
        A2[i] = f2b(We2[c * 64 + out]);
        A3[i] = f2b(Wc1[c * 64 + out]);
    }
    if (t < 64) {
        bv[0][t] = be1[t]; bv[1][t] = We1[128 * 64 + t];
        bv[2][t] = be2[t]; bv[3][t] = bc1[t]; bv[4][t] = Wc2[t];
    }
    __syncthreads();

    const int lane = t & 63;
    const int l16 = lane & 15, lq = lane >> 4;
    const int stride = gridDim.x * 8;
    const int wid = (blockIdx.x << 3) + (t >> 6);
    const int ntile = E >> 4;
    const int last = ntile - 1;
    unsigned* st = stl[t >> 6];

    int tile = wid;
    if (tile >= ntile) return;

    // ---------------- prologue: tile 0 data + tile 1 indices
    int eC = (tile << 4) + l16;
    unsigned pC = spack[eC];
    int rC = (int)(pC & 0xffffu), cC = (int)(pC >> 16);
    u16x8 hr0, hr1, hc0, hc1;
    {
        const u16x8* hr = reinterpret_cast<const u16x8*>(hb + (size_t)rC * 64);
        const u16x8* hc = reinterpret_cast<const u16x8*>(hb + (size_t)cC * 64);
        hr0 = hr[lq]; hr1 = hr[4 + lq]; hc0 = hc[lq]; hc1 = hc[4 + lq];
    }
    float px = 0.f, py = 0.f, pz = 0.f;
    if (lq < 2) {
        int node = (lq == 0) ? rC : cC;
        const float* pp = coord + (size_t)node * 3;
        px = pp[0]; py = pp[1]; pz = pp[2];
    }
    int t1 = tile + stride;
    int tn = (t1 < ntile) ? t1 : last;
    unsigned pN = spack[(tn << 4) + l16];
    int rN = (int)(pN & 0xffffu), cN = (int)(pN >> 16);

    for (; tile < ntile; ) {
        // ---- stage 1: issue next tile's h/coord loads
        u16x8 nr0, nr1, nc0, nc1;
        {
            const u16x8* hr = reinterpret_cast<const u16x8*>(hb + (size_t)rN * 64);
            const u16x8* hc = reinterpret_cast<const u16x8*>(hb + (size_t)cN * 64);
            nr0 = hr[lq]; nr1 = hr[4 + lq]; nc0 = hc[lq]; nc1 = hc[4 + lq];
        }
        float npx = 0.f, npy = 0.f, npz = 0.f;
        if (lq < 2) {
            int node = (lq == 0) ? rN : cN;
            const float* pp = coord + (size_t)node * 3;
            npx = pp[0]; npy = pp[1]; npz = pp[2];
        }
        // ---- stage 2: issue tile+2 index loads
        int t2 = tile + 2 * stride;
        int t2c = (t2 < ntile) ? t2 : last;
        unsigned pNN = spack[(t2c << 4) + l16];
        int rNN = (int)(pNN & 0xffffu), cNN = (int)(pNN >> 16);

        // ---- stage 3: compute current tile
        float prx = __shfl(px, l16, 64), pry = __shfl(py, l16, 64), prz = __shfl(pz, l16, 64);
        float pcx = __shfl(px, 16 + l16, 64), pcy = __shfl(py, 16 + l16, 64), pcz = __shfl(pz, 16 + l16, 64);
        float dx = prx - pcx, dy = pry - pcy, dz = prz - pcz;
        float rad = dx * dx + dy * dy + dz * dz;

        bf16x8 bR[2] = { __builtin_bit_cast(bf16x8, hr0), __builtin_bit_cast(bf16x8, hr1) };
        bf16x8 bC[2] = { __builtin_bit_cast(bf16x8, hc0), __builtin_bit_cast(bf16x8, hc1) };

        // layer 1
        f32x4 a1[4];
#pragma unroll
        for (int mt = 0; mt < 4; ++mt)
            a1[mt] = *reinterpret_cast<const f32x4*>(&bv[0][mt * 16 + lq * 4]);
#pragma unroll
        for (int ks = 0; ks < 2; ++ks)
#pragma unroll
            for (int mt = 0; mt < 4; ++mt)
                a1[mt] = mfma16(ldsA(A1, mt * 4 + ks, lane), bR[ks], a1[mt]);
#pragma unroll
        for (int ks = 0; ks < 2; ++ks)
#pragma unroll
            for (int mt = 0; mt < 4; ++mt)
                a1[mt] = mfma16(ldsA(A1, mt * 4 + 2 + ks, lane), bC[ks], a1[mt]);
#pragma unroll
        for (int mt = 0; mt < 4; ++mt) {
            f32x4 wv = *reinterpret_cast<const f32x4*>(&bv[1][mt * 16 + lq * 4]);
#pragma unroll
            for (int rr = 0; rr < 4; ++rr)
                a1[mt][rr] = fmaxf(a1[mt][rr] + rad * wv[rr], 0.f);
        }

        // layer 2
        bf16x8 b2[2] = { cvt8(a1[0], a1[1]), cvt8(a1[2], a1[3]) };
        f32x4 a2[4];
#pragma unroll
        for (int mt = 0; mt < 4; ++mt)
            a2[mt] = *reinterpret_cast<const f32x4*>(&bv[2][mt * 16 + lq * 4]);
#pragma unroll
        for (int ks = 0; ks < 2; ++ks)
#pragma unroll
            for (int mt = 0; mt < 4; ++mt)
                a2[mt] = mfma16(ldsA(A2, mt * 2 + ks, lane), b2[ks], a2[mt]);
#pragma unroll
        for (int mt = 0; mt < 4; ++mt)
#pragma unroll
            for (int rr = 0; rr < 4; ++rr)
                a2[mt][rr] = fmaxf(a2[mt][rr], 0.f);

        // ---- stash a2 (channel-pair major, swizzled): st[cp][l16 ^ (cp&12)]
#pragma unroll
        for (int mt = 0; mt < 4; ++mt) {
            int cp0 = mt * 8 + lq * 2;
            int sw  = l16 ^ (cp0 & 12);
            st[(cp0 + 0) * 16 + sw] = pk2(a2[mt][0], a2[mt][1]);
            st[(cp0 + 1) * 16 + sw] = pk2(a2[mt][2], a2[mt][3]);
        }

        // ---- gate (MFMAs overlap the stash writes)
        bf16x8 b3[2] = { cvt8(a2[0], a2[1]), cvt8(a2[2], a2[3]) };
        f32x4 a3[4];
#pragma unroll
        for (int mt = 0; mt < 4; ++mt)
            a3[mt] = *reinterpret_cast<const f32x4*>(&bv[3][mt * 16 + lq * 4]);
#pragma unroll
        for (int ks = 0; ks < 2; ++ks)
#pragma unroll
            for (int mt = 0; mt < 4; ++mt)
                a3[mt] = mfma16(ldsA(A3, mt * 2 + ks, lane), b3[ks], a3[mt]);
        float gg = 0.f;
#pragma unroll
        for (int mt = 0; mt < 4; ++mt) {
            f32x4 wv = *reinterpret_cast<const f32x4*>(&bv[4][mt * 16 + lq * 4]);
#pragma unroll
            for (int rr = 0; rr < 4; ++rr)
                gg += fmaxf(a3[mt][rr], 0.f) * wv[rr];
        }
        gg += __shfl_xor(gg, 16, 64);
        gg += __shfl_xor(gg, 32, 64);

        float dsel = (lq == 0) ? dx : (lq == 1) ? dy : dz;
        float val  = fminf(fmaxf(dsel * gg, -100.f), 100.f);

        // ---- coord stash rows {x,y},{z,1}: cp = 32, 33 (swizzle = 0 there)
        float vy = __shfl(val, 16 + l16, 64);          // y from lq==1 lane
        if (lq == 0) st[32 * 16 + l16] = pk2(val, vy);
        if (lq == 2) st[33 * 16 + l16] = pk2(val, 1.0f);

        // ---- selection fragment: sel[k][n] = (row(edge k) == row(edge n))
        u16x8 sv;
#pragma unroll
        for (int j = 0; j < 8; ++j) {
            int ks = lq * 8 + j;
            int rk = __shfl(rC, ks & 15, 64);
            sv[j] = (ks < 16 && rk == rC) ? (unsigned short)0x3F80 : (unsigned short)0;
        }
        bf16x8 self = __builtin_bit_cast(bf16x8, sv);

        // ---- per-tile partial sums: 5 MFMAs (4 channel tiles + coord tile)
        f32x4 pg[5];
#pragma unroll
        for (int k = 0; k < 5; ++k) pg[k] = (f32x4){0.f, 0.f, 0.f, 0.f};
        const int elo = (lq & 1) << 3;
#pragma unroll
        for (int tt = 0; tt < 5; ++tt) {
            int cpb = (tt < 4) ? (tt * 8 + (l16 >> 1)) : (32 + ((l16 >> 1) & 1));
            int c   = cpb & 12;
            u32x4 wa = *reinterpret_cast<const u32x4*>(st + cpb * 16 + (elo ^ c));
            u32x4 wb = *reinterpret_cast<const u32x4*>(st + cpb * 16 + ((elo + 4) ^ c));
            u16x8 av;
#pragma unroll
            for (int j = 0; j < 4; ++j) {
                av[j]     = (l16 & 1) ? (unsigned short)(wa[j] >> 16)
                                      : (unsigned short)(wa[j] & 0xffffu);
                av[4 + j] = (l16 & 1) ? (unsigned short)(wb[j] >> 16)
                                      : (unsigned short)(wb[j] & 0xffffu);
            }
            pg[tt] = mfma16(__builtin_bit_cast(bf16x8, av), self, pg[tt]);
        }

        // ---- write partials back to the stash (feat stash fully consumed)
#pragma unroll
        for (int mt = 0; mt < 4; ++mt) {
            int cp0 = mt * 8 + lq * 2;
            int sw  = l16 ^ (cp0 & 12);
            st[(cp0 + 0) * 16 + sw] = pk2(pg[mt][0], pg[mt][1]);
            st[(cp0 + 1) * 16 + sw] = pk2(pg[mt][2], pg[mt][3]);
        }

        // ---- leader detection (run starts within the tile)
        int rprev = __shfl(rC, (lane & 48) | ((l16 + 15) & 15), 64);
        bool lead = (l16 == 0) || (rprev != rC);

        // coord partial scatter: 4 f32 atomics per leader (ws, L2-merged)
        if (lead && lq == 0) {
#pragma unroll
            for (int rr = 0; rr < 4; ++rr)
                atomicAdd(&cacc[(size_t)rC * 4 + rr], pg[4][rr]);
        }

        // agg partial scatter: pk-bf16 rows into ws, two leaders per 64-lane op
        {
            unsigned m = (unsigned)(__ballot(lead) & 0xFFFFull);
            const int cp = lane & 31;
            const int half = lane >> 5;
            while (m) {
                int s0 = __builtin_ctz(m); m &= m - 1;
                int s1 = 16;
                if (m) { s1 = __builtin_ctz(m); m &= m - 1; }
                int s = half ? s1 : s0;
                if (s < 16) {
                    int rw = __shfl(rC, s, 64);
                    unsigned pkd = st[cp * 16 + (s ^ (cp & 12))];
                    atom_pk(aggb + (size_t)rw * 64 + cp * 2, pkd);
                }
            }
        }

        // ---- rotate
        tile = t1; t1 = tile + stride;
        rC = rN; cC = cN; rN = rNN; cN = cNN;
        hr0 = nr0; hr1 = nr1; hc0 = nc0; hc1 = nc1;
        px = npx; py = npy; pz = npz;
    }
}

// ===================== FALLBACK EDGE PASS (atomic, f32) =====================
__global__ __launch_bounds__(512, 4) void egcl_edge_fb(
    const float* __restrict__ h, const float* __restrict__ coord,
    const int* __restrict__ erow, const int* __restrict__ ecol,
    const float* __restrict__ We1, const float* __restrict__ be1,
    const float* __restrict__ We2, const float* __restrict__ be2,
    const float* __restrict__ Wc1, const float* __restrict__ bc1,
    const float* __restrict__ Wc2,
    float* __restrict__ aggf, float* __restrict__ cacc, int E)
{
    __shared__ __align__(16) unsigned short A1[16 * 512];
    __shared__ __align__(16) unsigned short A2[8 * 512];
    __shared__ __align__(16) unsigned short A3[8 * 512];
    __shared__ __align__(16) float bv[5][64];

    const int t = threadIdx.x;
    for (int i = t; i < 8192; i += 512) {
        int j = i & 7, lane = (i >> 3) & 63, fi = i >> 9;
        int mt = fi >> 2, ks = fi & 3;
        int in_ch = ks * 32 + ((lane >> 4) << 3) + j;
        int out   = mt * 16 + (lane & 15);
        A1[i] = f2b(We1[in_ch * 64 + out]);
    }
    for (int i = t; i < 4096; i += 512) {
        int j = i & 7, lane = (i >> 3) & 63, fi = i >> 9;
        int mt = fi >> 1, ks = fi & 1;
        int c   = (ks * 2 + (j >> 2)) * 16 + ((lane >> 4) & 3) * 4 + (j & 3);
        int out = mt * 16 + (lane & 15);
        A2[i] = f2b(We2[c * 64 + out]);
        A3[i] = f2b(Wc1[c * 64 + out]);
    }
    if (t < 64) {
        bv[0][t] = be1[t]; bv[1][t] = We1[128 * 64 + t];
        bv[2][t] = be2[t]; bv[3][t] = bc1[t]; bv[4][t] = Wc2[t];
    }
    __syncthreads();

    const int lane = t & 63;
    const int l16 = lane & 15, lq = lane >> 4;
    const int stride = gridDim.x * 8;
    const int wid = (blockIdx.x << 3) + (t >> 6);
    const int ntile = E >> 4;

    for (int tile = wid; tile < ntile; tile += stride) {
        const int e = (tile << 4) + l16;
        const int r = erow[e], c = ecol[e];
        const float* pr = coord + (size_t)r * 3;
        const float* pc = coord + (size_t)c * 3;
        float dx = pr[0] - pc[0], dy = pr[1] - pc[1], dz = pr[2] - pc[2];
        float rad = dx * dx + dy * dy + dz * dz;
        const f32x4* hr = reinterpret_cast<const f32x4*>(h + (size_t)r * 64);
        const f32x4* hc = reinterpret_cast<const f32x4*>(h + (size_t)c * 64);
        bf16x8 bR[2], bC[2];
#pragma unroll
        for (int ks = 0; ks < 2; ++ks) {
            bR[ks] = cvt8(hr[ks * 8 + lq * 2], hr[ks * 8 + lq * 2 + 1]);
            bC[ks] = cvt8(hc[ks * 8 + lq * 2], hc[ks * 8 + lq * 2 + 1]);
        }
        f32x4 a1[4];
#pragma unroll
        for (int mt = 0; mt < 4; ++mt)
            a1[mt] = *reinterpret_cast<const f32x4*>(&bv[0][mt * 16 + lq * 4]);
#pragma unroll
        for (int ks = 0; ks < 2; ++ks)
#pragma unroll
            for (int mt = 0; mt < 4; ++mt)
                a1[mt] = mfma16(ldsA(A1, mt * 4 + ks, lane), bR[ks], a1[mt]);
#pragma unroll
        for (int ks = 0; ks < 2; ++ks)
#pragma unroll
            for (int mt = 0; mt < 4; ++mt)
                a1[mt] = mfma16(ldsA(A1, mt * 4 + 2 + ks, lane), bC[ks], a1[mt]);
#pragma unroll
        for (int mt = 0; mt < 4; ++mt) {
            f32x4 wv = *reinterpret_cast<const f32x4*>(&bv[1][mt * 16 + lq * 4]);
#pragma unroll
            for (int rr = 0; rr < 4; ++rr)
                a1[mt][rr] = fmaxf(a1[mt][rr] + rad * wv[rr], 0.f);
        }
        bf16x8 b2[2] = { cvt8(a1[0], a1[1]), cvt8(a1[2], a1[3]) };
        f32x4 a2[4];
#pragma unroll
        for (int mt = 0; mt < 4; ++mt)
            a2[mt] = *reinterpret_cast<const f32x4*>(&bv[2][mt * 16 + lq * 4]);
#pragma unroll
        for (int ks = 0; ks < 2; ++ks)
#pragma unroll
            for (int mt = 0; mt < 4; ++mt)
                a2[mt] = mfma16(ldsA(A2, mt * 2 + ks, lane), b2[ks], a2[mt]);
#pragma unroll
        for (int mt = 0; mt < 4; ++mt)
#pragma unroll
            for (int rr = 0; rr < 4; ++rr) {
                a2[mt][rr] = fmaxf(a2[mt][rr], 0.f);
                atomicAdd(&aggf[(size_t)r * 64 + mt * 16 + lq * 4 + rr], a2[mt][rr]);
            }
        bf16x8 b3[2] = { cvt8(a2[0], a2[1]), cvt8(a2[2], a2[3]) };
        f32x4 a3[4];
#pragma unroll
        for (int mt = 0; mt < 4; ++mt)
            a3[mt] = *reinterpret_cast<const f32x4*>(&bv[3][mt * 16 + lq * 4]);
#pragma unroll
        for (int ks = 0; ks < 2; ++ks)
#pragma unroll
            for (int mt = 0; mt < 4; ++mt)
                a3[mt] = mfma16(ldsA(A3, mt * 2 + ks, lane), b3[ks], a3[mt]);
        float gg = 0.f;
#pragma unroll
        for (int mt = 0; mt < 4; ++mt) {
            f32x4 wv = *reinterpret_cast<const f32x4*>(&bv[4][mt * 16 + lq * 4]);
#pragma unroll
            for (int rr = 0; rr < 4; ++rr)
                gg += fmaxf(a3[mt][rr], 0.f) * wv[rr];
        }
        gg += __shfl_xor(gg, 16, 64);
        gg += __shfl_xor(gg, 32, 64);
        float dsel = (lq == 0) ? dx : (lq == 1) ? dy : dz;
        float val  = (lq == 3) ? 1.0f : fminf(fmaxf(dsel * gg, -100.f), 100.f);
        atomicAdd(&cacc[(size_t)r * 4 + lq], val);
    }
}

// ============================== NODE PASS ==============================
__device__ inline void stage_wblock(unsigned short* dst, const float* src, int t, int nthr) {
    for (int i = t; i < 4096; i += nthr) {
        int k = i >> 6, n = i & 63;
        int pos = (((n >> 4) * 2 + (k >> 5)) * 64 + ((((k >> 3) & 3) << 4) | (n & 15))) * 8 + (k & 7);
        dst[pos] = f2b(src[i]);
    }
}

__device__ inline bf16x8 ldsB(const unsigned short* base, int nt, int ks, int lane) {
    return __builtin_bit_cast(bf16x8,
        *reinterpret_cast<const u16x8*>(base + (((nt * 2 + ks) * 64 + lane) << 3)));
}

template<bool PK>
__global__ __launch_bounds__(256) void egcl_node(
    const float* __restrict__ h, const unsigned short* __restrict__ hb,
    const float* __restrict__ aggf, const unsigned short* __restrict__ aggb,
    const float* __restrict__ Wn1, const float* __restrict__ bn1,
    const float* __restrict__ Wn2, const float* __restrict__ bn2,
    float* __restrict__ hout, int N)
{
    __shared__ __align__(16) unsigned short wlds[3][4096];
    __shared__ __align__(16) unsigned short mlds[4][16 * 72];
    __shared__ float bn1l[64], bn2l[64];

    const int t = threadIdx.x;
    stage_wblock(wlds[0], Wn1, t, 256);
    stage_wblock(wlds[1], Wn1 + 64 * 64, t, 256);
    stage_wblock(wlds[2], Wn2, t, 256);
    if (t < 64) { bn1l[t] = bn1[t]; bn2l[t] = bn2[t]; }
    __syncthreads();

    const int wave = t >> 6, lane = t & 63;
    const int l16 = lane & 15, lq = lane >> 4;
    const int ntile = N >> 4;
    unsigned short* ml = mlds[wave];

    for (int tile = blockIdx.x * 4 + wave; tile < ntile; tile += gridDim.x * 4) {
        const int nb = tile << 4;
        bf16x8 fH[2], fA[2];
        if constexpr (PK) {
            const u16x8* ph = reinterpret_cast<const u16x8*>(hb + (size_t)(nb + l16) * 64);
            const u16x8* pa = reinterpret_cast<const u16x8*>(aggb + (size_t)(nb + l16) * 64);
#pragma unroll
            for (int ks = 0; ks < 2; ++ks) {
                fH[ks] = __builtin_bit_cast(bf16x8, ph[ks * 4 + lq]);
                fA[ks] = __builtin_bit_cast(bf16x8, pa[ks * 4 + lq]);
            }
        } else {
            const f32x4* ph = reinterpret_cast<const f32x4*>(h + (size_t)(nb + l16) * 64);
            const f32x4* pa = reinterpret_cast<const f32x4*>(aggf + (size_t)(nb + l16) * 64);
#pragma unroll
            for (int ks = 0; ks < 2; ++ks) {
                fH[ks] = cvt8(ph[ks * 8 + lq * 2], ph[ks * 8 + lq * 2 + 1]);
                fA[ks] = cvt8(pa[ks * 8 + lq * 2], pa[ks * 8 + lq * 2 + 1]);
            }
        }
        f32x4 acc[4];
#pragma unroll
        for (int nt = 0; nt < 4; ++nt) { float b = bn1l[nt * 16 + l16]; acc[nt] = (f32x4){b, b, b, b}; }
#pragma unroll
        for (int ks = 0; ks < 2; ++ks)
#pragma unroll
            for (int nt = 0; nt < 4; ++nt)
                acc[nt] = mfma16(fH[ks], ldsB(wlds[0], nt, ks, lane), acc[nt]);
#pragma unroll
        for (int ks = 0; ks < 2; ++ks)
#pragma unroll
            for (int nt = 0; nt < 4; ++nt)
                acc[nt] = mfma16(fA[ks], ldsB(wlds[1], nt, ks, lane), acc[nt]);
#pragma unroll
        for (int nt = 0; nt < 4; ++nt)
#pragma unroll
            for (int r = 0; r < 4; ++r)
                ml[(lq * 4 + r) * 72 + nt * 16 + l16] = f2b(fmaxf(acc[nt][r], 0.f));
        bf16x8 fM[2];
#pragma unroll
        for (int ks = 0; ks < 2; ++ks)
            fM[ks] = __builtin_bit_cast(bf16x8,
                *reinterpret_cast<const u16x8*>(ml + l16 * 72 + ks * 32 + lq * 8));
        f32x4 acc2[4];
#pragma unroll
        for (int nt = 0; nt < 4; ++nt) { float b = bn2l[nt * 16 + l16]; acc2[nt] = (f32x4){b, b, b, b}; }
#pragma unroll
        for (int ks = 0; ks < 2; ++ks)
#pragma unroll
            for (int nt = 0; nt < 4; ++nt)
                acc2[nt] = mfma16(fM[ks], ldsB(wlds[2], nt, ks, lane), acc2[nt]);
#pragma unroll
        for (int nt = 0; nt < 4; ++nt)
#pragma unroll
            for (int r = 0; r < 4; ++r) {
                size_t idx = (size_t)(nb + lq * 4 + r) * 64 + nt * 16 + l16;
                hout[idx] = h[idx] + acc2[nt][r];
            }
    }
}

// ---------------------------------------------------------------- helpers
__global__ void f32_to_bf16(const float* __restrict__ src, unsigned short* __restrict__ dst, int n8)
{
    int i = blockIdx.x * 256 + threadIdx.x;
    if (i < n8) {
        const f32x4* p = reinterpret_cast<const f32x4*>(src + (size_t)i * 8);
        bf16x8 v = cvt8(p[0], p[1]);
        reinterpret_cast<u16x8*>(dst)[i] = __builtin_bit_cast(u16x8, v);
    }
}

__global__ void egcl_coord(const float* __restrict__ cacc, float* __restrict__ cout, int N)
{
    int n = blockIdx.x * 256 + threadIdx.x;
    if (n < N) {
        f32x4 c = *reinterpret_cast<const f32x4*>(cacc + (size_t)n * 4);
        float inv = 1.f / fmaxf(c[3], 1.f);
        cout[n * 3 + 0] = c[0] * inv;
        cout[n * 3 + 1] = c[1] * inv;
        cout[n * 3 + 2] = c[2] * inv;
    }
}

extern "C" void kernel_launch(void* const* d_in, const int* in_sizes, int n_in,
                              void* d_out, int out_size, void* d_ws, size_t ws_size,
                              hipStream_t stream)
{
    const float* h     = (const float*)d_in[0];
    const float* coord = (const float*)d_in[1];
    const int*   eidx  = (const int*)d_in[2];
    const float* We1 = (const float*)d_in[3];  const float* be1 = (const float*)d_in[4];
    const float* We2 = (const float*)d_in[5];  const float* be2 = (const float*)d_in[6];
    const float* Wn1 = (const float*)d_in[7];  const float* bn1 = (const float*)d_in[8];
    const float* Wn2 = (const float*)d_in[9];  const float* bn2 = (const float*)d_in[10];
    const float* Wc1 = (const float*)d_in[11]; const float* bc1 = (const float*)d_in[12];
    const float* Wc2 = (const float*)d_in[13];

    const int N = in_sizes[0] / 64;
    const int E = in_sizes[2] / 2;

    float* hout = (float*)d_out;
    float* cout = hout + (size_t)N * 64;

    const int ntileN = N >> 4;
    const int nblkN  = (ntileN + 3) / 4;

    // workspace layout (region [0,1MB) reused: CSR temporaries, then cacc)
    int*      cnt   = (int*)d_ws;                               // N ints
    int*      off   = (int*)((char*)d_ws + (256u << 10));       // N+1 ints
    int*      woff  = (int*)((char*)d_ws + (512u << 10));       // N ints
    int*      bsum  = (int*)((char*)d_ws + (768u << 10));       // 128 ints
    float*    cacc  = (float*)d_ws;                             // N*4 f32 (after CSR)
    unsigned* spack = (unsigned*)((char*)d_ws + (1u << 20));    // E u32
    unsigned short* hb   = (unsigned short*)((char*)d_ws + (5u << 20));  // N*64 bf16
    unsigned short* aggb = (unsigned short*)((char*)d_ws + (12u << 20)); // N*64 bf16

    const size_t need_sorted = (12u << 20) + (size_t)N * 128;
    const bool use_sorted = (ws_size >= need_sorted) && N > 0 && (N % 16 == 0)
                            && (N <= 65536) && (E % 16 == 0)
                            && ((size_t)E * 4 <= (4u << 20));

    if (use_sorted) {
        hipMemsetAsync(cnt, 0, (size_t)N * sizeof(int), stream);
        int n8 = N * 8;
        f32_to_bf16<<<(n8 + 255) / 256, 256, 0, stream>>>(h, hb, n8);
        k_hist<<<(E + 255) / 256, 256, 0, stream>>>(eidx, cnt, E);
        k_scan1<<<128, 256, 0, stream>>>(cnt, bsum, N);
        k_scan2<<<1, 128, 0, stream>>>(bsum);
        k_scan3<<<128, 256, 0, stream>>>(cnt, bsum, off, woff, N, E);
        k_scatter<<<(E + 255) / 256, 256, 0, stream>>>(eidx, eidx + E, woff, spack, E);
        // CSR temporaries dead from here; reuse region for cacc
        hipMemsetAsync(cacc, 0, (size_t)N * 4 * sizeof(float), stream);
        hipMemsetAsync(aggb, 0, (size_t)N * 128, stream);
        egcl_edge_srt<<<2048, 512, 0, stream>>>(hb, coord, spack,
                                                We1, be1, We2, be2, Wc1, bc1, Wc2,
                                                aggb, cacc, E);
        egcl_node<true><<<nblkN, 256, 0, stream>>>(h, hb, nullptr, aggb,
                                                   Wn1, bn1, Wn2, bn2, hout, N);
        egcl_coord<<<(N + 255) / 256, 256, 0, stream>>>(cacc, cout, N);
    } else {
        float* aggf = hout;
        hipMemsetAsync(cacc, 0, (size_t)N * 4 * sizeof(float), stream);
        hipMemsetAsync(aggf, 0, (size_t)N * 64 * sizeof(float), stream);
        egcl_edge_fb<<<2048, 512, 0, stream>>>(h, coord, eidx, eidx + E,
                                               We1, be1, We2, be2, Wc1, bc1, Wc2,
                                               aggf, cacc, E);
        egcl_node<false><<<nblkN, 256, 0, stream>>>(h, nullptr, aggf, nullptr,
                                                    Wn1, bn1, Wn2, bn2, hout, N);
        egcl_coord<<<(N + 255) / 256, 256, 0, stream>>>(cacc, cout, N);
    }
}